// Round 6
// baseline (1712.752 us; speedup 1.0000x reference)
//
#include <hip/hip_runtime.h>
#include <stdint.h>

#define N0 30000
#define N1 6000
#define FDIM 1024
#define HDIM 512
#define E00 600000
#define E01 300000
#define E10 300000
#define E11A 400000
#define E11B 400000
#define NE_TOT (E00 + E01 + E10 + E11A + E11B)

typedef __attribute__((ext_vector_type(4))) float f32x4;
typedef __attribute__((ext_vector_type(8))) __bf16 bf16x8;

// ---------- helpers ----------
__device__ __forceinline__ unsigned short f2bf(float f) {
  unsigned u = __float_as_uint(f);
  u += 0x7fffu + ((u >> 16) & 1u);   // round-to-nearest-even
  return (unsigned short)(u >> 16);
}

__device__ __forceinline__ void gload16(const void* g, void* l) {
  __builtin_amdgcn_global_load_lds((const __attribute__((address_space(1))) void*)g,
                                   (__attribute__((address_space(3))) void*)l, 16, 0, 0);
}

// ---------- conversion kernels ----------
__global__ void conv_bf16_kernel(const float* __restrict__ src, unsigned short* __restrict__ dst, int n4) {
  int gid = blockIdx.x * blockDim.x + threadIdx.x;
  if (gid >= n4) return;
  float4 v = ((const float4*)src)[gid];
  ushort4 o;
  o.x = f2bf(v.x); o.y = f2bf(v.y); o.z = f2bf(v.z); o.w = f2bf(v.w);
  ((ushort4*)dst)[gid] = o;
}

// Layer-1 weights: N-stacked, Bt[n][k] (k = FDIM).
__global__ void conv_weights_kernel(const float* __restrict__ w00, const float* __restrict__ w10,
                                    const float* __restrict__ w01, const float* __restrict__ w11a,
                                    const float* __restrict__ w11b,
                                    unsigned short* __restrict__ dst0, unsigned short* __restrict__ dst1, int K) {
  int gid = blockIdx.x * blockDim.x + threadIdx.x;
  int total0 = 1024 * K;
  int total1 = 1536 * K;
  if (gid < total0) {
    int n = gid / K, k = gid - n * K;
    const float* w = (n < 512) ? w00 : w10;
    int nn = n & 511;
    dst0[gid] = f2bf(w[(size_t)k * 512 + nn]);
  } else if (gid < total0 + total1) {
    int g = gid - total0;
    int n = g / K, k = g - n * K;
    const float* w = (n < 512) ? w01 : ((n < 1024) ? w11a : w11b);
    int nn = n & 511;
    dst1[g] = f2bf(w[(size_t)k * 512 + nn]);
  }
}

// Layers-2/3 weights: K-stacked, Bt[n][k], n in [0,512).
__global__ void conv_wk_kernel(const float* __restrict__ w00, const float* __restrict__ w01,
                               const float* __restrict__ w10, const float* __restrict__ w11a,
                               const float* __restrict__ w11b,
                               unsigned short* __restrict__ dst0, unsigned short* __restrict__ dst1) {
  int gid = blockIdx.x * blockDim.x + threadIdx.x;
  const int T0 = 512 * 1024;
  const int T1 = 512 * 1536;
  if (gid < T0) {
    int n = gid >> 10, k = gid & 1023;
    const float* w = (k < 512) ? w00 : w01;
    dst0[gid] = f2bf(w[(size_t)(k & 511) * 512 + n]);
  } else if (gid < T0 + T1) {
    int g = gid - T0;
    int n = g / 1536, k = g - n * 1536;
    const float* w = (k < 512) ? w10 : ((k < 1024) ? w11a : w11b);
    dst1[g] = f2bf(w[(size_t)(k & 511) * 512 + n]);
  }
}

// ---------- CSR build ----------
__global__ void zero_ints(int* p, int n) {
  int g = blockIdx.x * blockDim.x + threadIdx.x;
  if (g < n) p[g] = 0;
}

__global__ void hist5(const int* __restrict__ r0, const int* __restrict__ r1, const int* __restrict__ r2,
                      const int* __restrict__ r3, const int* __restrict__ r4,
                      int* c0, int* c1, int* c2, int* c3, int* c4) {
  int g = blockIdx.x * blockDim.x + threadIdx.x;
  const int* r; int* c; int e;
  if (g < E00) { r = r0; c = c0; e = g; }
  else if (g < E00 + E01) { r = r1; c = c1; e = g - E00; }
  else if (g < E00 + E01 + E10) { r = r2; c = c2; e = g - (E00 + E01); }
  else if (g < E00 + E01 + E10 + E11A) { r = r3; c = c3; e = g - (E00 + E01 + E10); }
  else if (g < NE_TOT) { r = r4; c = c4; e = g - (E00 + E01 + E10 + E11A); }
  else return;
  atomicAdd(&c[r[e]], 1);
}

__global__ __launch_bounds__(1024) void scan5p(int* c0, int* rp0, int* c1, int* rp1,
                                               int* c2, int* rp2, int* c3, int* rp3,
                                               int* c4, int* rp4) {
  int b = blockIdx.x;
  int* cnt; int* rp; int n;
  if (b == 0) { cnt = c0; rp = rp0; n = N0; }
  else if (b == 1) { cnt = c1; rp = rp1; n = N0; }
  else if (b == 2) { cnt = c2; rp = rp2; n = N1; }
  else if (b == 3) { cnt = c3; rp = rp3; n = N1; }
  else { cnt = c4; rp = rp4; n = N1; }
  __shared__ int wsum[16];
  const int tid = threadIdx.x, lane = tid & 63, w = tid >> 6;
  int carry = 0;
  for (int base = 0; base < n; base += 1024) {
    int i = base + tid;
    int v = (i < n) ? cnt[i] : 0;
    int x = v;
    #pragma unroll
    for (int d = 1; d < 64; d <<= 1) {
      int y = __shfl_up(x, d, 64);
      if (lane >= d) x += y;
    }
    if (lane == 63) wsum[w] = x;
    __syncthreads();
    if (w == 0) {
      int t = (lane < 16) ? wsum[lane] : 0;
      #pragma unroll
      for (int d = 1; d < 16; d <<= 1) {
        int y = __shfl_up(t, d, 64);
        if (lane >= d) t += y;
      }
      if (lane < 16) wsum[lane] = t;
    }
    __syncthreads();
    int wpref = (w > 0) ? wsum[w - 1] : 0;
    int excl = carry + wpref + (x - v);
    if (i < n) { rp[i] = excl; cnt[i] = excl; }
    carry += wsum[15];
    __syncthreads();
  }
  if (tid == 0) rp[n] = carry;
}

__global__ void scatter5(const int* __restrict__ r0, const int* __restrict__ q0, const float* __restrict__ v0,
                         int* cur0, int* sc0, float* sv0,
                         const int* __restrict__ r1, const int* __restrict__ q1, const float* __restrict__ v1,
                         int* cur1, int* sc1, float* sv1,
                         const int* __restrict__ r2, const int* __restrict__ q2, const float* __restrict__ v2,
                         int* cur2, int* sc2, float* sv2,
                         const int* __restrict__ r3, const int* __restrict__ q3, const float* __restrict__ v3,
                         int* cur3, int* sc3, float* sv3,
                         const int* __restrict__ r4, const int* __restrict__ q4, const float* __restrict__ v4,
                         int* cur4, int* sc4, float* sv4) {
  int g = blockIdx.x * blockDim.x + threadIdx.x;
  const int* r; const int* q; const float* v; int* cur; int* sc; float* sv; int e;
  if (g < E00) { r = r0; q = q0; v = v0; cur = cur0; sc = sc0; sv = sv0; e = g; }
  else if (g < E00 + E01) { r = r1; q = q1; v = v1; cur = cur1; sc = sc1; sv = sv1; e = g - E00; }
  else if (g < E00 + E01 + E10) { r = r2; q = q2; v = v2; cur = cur2; sc = sc2; sv = sv2; e = g - (E00 + E01); }
  else if (g < E00 + E01 + E10 + E11A) { r = r3; q = q3; v = v3; cur = cur3; sc = sc3; sv = sv3; e = g - (E00 + E01 + E10); }
  else if (g < NE_TOT) { r = r4; q = q4; v = v4; cur = cur4; sc = sc4; sv = sv4; e = g - (E00 + E01 + E10 + E11A); }
  else return;
  int row = r[e];
  int p = atomicAdd(&cur[row], 1);
  sc[p] = q[e];
  sv[p] = v[e];
}

// ---------- bf16 MFMA GEMM: C = A[M][K] @ Bt[N][K]^T ----------
// MODE 0: bf16 store; MODE 1: bf16 + relu; MODE 2: f32 NT store (no relu).
#define BM 128
#define BN 128
#define BK 64

struct GemmArgs {
  const unsigned short* A;
  const unsigned short* Bt;
  void* C;
  int M, N, K, nbx, ldc, nwg;
};

template<int MODE>
__device__ __forceinline__ void gemm_body(const GemmArgs& g, int orig) {
  __shared__ unsigned short As[BM * BK];
  __shared__ unsigned short Bs[BN * BK];
  // bijective XCD-aware swizzle (m204) over the local sub-grid
  const int nwg = g.nwg;
  const int q = nwg >> 3, rr = nwg & 7;
  const int xcd = orig & 7, pos = orig >> 3;
  const int wg = (xcd < rr ? xcd * (q + 1) : rr * (q + 1) + (xcd - rr) * q) + pos;
  const int bx = wg % g.nbx;
  const int by = wg / g.nbx;

  const int tid = threadIdx.x;
  const int lane = tid & 63;
  const int wid = tid >> 6;
  const int m0 = bx * BM;
  const int n0 = by * BN;
  const int wm = (wid >> 1) * 64;
  const int wn = (wid & 1) * 64;
  const int M = g.M, K = g.K;

  f32x4 acc[4][4] = {};

  const int srow = wid * 32 + (lane >> 3);
  const int scol = (lane & 7) * 8;

  for (int k0 = 0; k0 < K; k0 += BK) {
    #pragma unroll
    for (int c = 0; c < 4; ++c) {
      int gr = m0 + srow + c * 8;
      if (gr > M - 1) gr = M - 1;
      gload16(g.A + (size_t)gr * K + k0 + scol, As + (wid * 32 + c * 8) * BK);
      int gn = n0 + srow + c * 8;
      gload16(g.Bt + (size_t)gn * K + k0 + scol, Bs + (wid * 32 + c * 8) * BK);
    }
    __syncthreads();
    #pragma unroll
    for (int ks = 0; ks < 2; ++ks) {
      bf16x8 af[4], bfr[4];
      #pragma unroll
      for (int i = 0; i < 4; i++)
        af[i] = *(const bf16x8*)(As + (wm + i * 16 + (lane & 15)) * BK + ks * 32 + (lane >> 4) * 8);
      #pragma unroll
      for (int j = 0; j < 4; j++)
        bfr[j] = *(const bf16x8*)(Bs + (wn + j * 16 + (lane & 15)) * BK + ks * 32 + (lane >> 4) * 8);
      #pragma unroll
      for (int i = 0; i < 4; i++)
        #pragma unroll
        for (int j = 0; j < 4; j++)
          acc[i][j] = __builtin_amdgcn_mfma_f32_16x16x32_bf16(af[i], bfr[j], acc[i][j], 0, 0, 0);
    }
    __syncthreads();
  }

  #pragma unroll
  for (int i = 0; i < 4; i++) {
    int rbase = m0 + wm + i * 16 + (lane >> 4) * 4;
    #pragma unroll
    for (int j = 0; j < 4; j++) {
      int col = n0 + wn + j * 16 + (lane & 15);
      #pragma unroll
      for (int r = 0; r < 4; r++) {
        int row = rbase + r;
        if (row < M) {
          float v = acc[i][j][r];
          if (MODE == 1) v = fmaxf(v, 0.f);
          if (MODE == 2)
            __builtin_nontemporal_store(v, &((float*)g.C)[(size_t)row * g.ldc + col]);
          else
            ((unsigned short*)g.C)[(size_t)row * g.ldc + col] = f2bf(v);
        }
      }
    }
  }
}

template<int MODE>
__global__ __launch_bounds__(256) void gemm_pair(GemmArgs ga, GemmArgs gb) {
  if ((int)blockIdx.x < ga.nwg) gemm_body<MODE>(ga, blockIdx.x);
  else gemm_body<MODE>(gb, blockIdx.x - ga.nwg);
}

// ---------- sliced SpMM gather core ----------
// A wave processes one (row, 64-col slice). 8-lane groups each gather one edge's
// 128B slice (16B/lane); group-reduce via shfl_xor(8,16,32).
__device__ __forceinline__ void acc8(float* acc, float v, const uint4& u) {
  acc[0] += v * __uint_as_float(u.x << 16);
  acc[1] += v * __uint_as_float(u.x & 0xffff0000u);
  acc[2] += v * __uint_as_float(u.y << 16);
  acc[3] += v * __uint_as_float(u.y & 0xffff0000u);
  acc[4] += v * __uint_as_float(u.z << 16);
  acc[5] += v * __uint_as_float(u.z & 0xffff0000u);
  acc[6] += v * __uint_as_float(u.w << 16);
  acc[7] += v * __uint_as_float(u.w & 0xffff0000u);
}

struct SSeg {
  const int* rp; const int* ci; const float* cv;
  const unsigned short* tbl;   // already offset to this segment's col base
  int ld;                      // row stride in elements
};

__device__ __forceinline__ void gather_slice(const SSeg& s, int r, int scol, int lane, float* acc) {
  int e  = __builtin_amdgcn_readfirstlane(s.rp[r]);
  int e1 = __builtin_amdgcn_readfirstlane(s.rp[r + 1]);
  const unsigned short* gb = s.tbl + scol + (lane & 7) * 8;
  const int g = lane >> 3;
  const int ld = s.ld;
  for (; e + 16 <= e1; e += 16) {
    int c0 = s.ci[e + g];
    int c1 = s.ci[e + 8 + g];
    float v0 = s.cv[e + g];
    float v1 = s.cv[e + 8 + g];
    uint4 u0 = *(const uint4*)(gb + (size_t)c0 * ld);
    uint4 u1 = *(const uint4*)(gb + (size_t)c1 * ld);
    acc8(acc, v0, u0);
    acc8(acc, v1, u1);
  }
  if (e + 8 <= e1) {
    int c0 = s.ci[e + g];
    float v0 = s.cv[e + g];
    uint4 u0 = *(const uint4*)(gb + (size_t)c0 * ld);
    acc8(acc, v0, u0);
    e += 8;
  }
  int rem = e1 - e;
  if (g < rem) {
    int c0 = s.ci[e + g];
    float v0 = s.cv[e + g];
    uint4 u0 = *(const uint4*)(gb + (size_t)c0 * ld);
    acc8(acc, v0, u0);
  }
}

__device__ __forceinline__ void reduce_groups(float* acc) {
  #pragma unroll
  for (int i = 0; i < 8; i++) {
    acc[i] += __shfl_xor(acc[i], 8, 64);
    acc[i] += __shfl_xor(acc[i], 16, 64);
    acc[i] += __shfl_xor(acc[i], 32, 64);
  }
}

struct S1Set {
  int nrows, nseg;
  SSeg s0, s1, s2;
  unsigned short* ebf;   // bf16 e0 (ld 512)
  float* outp;           // f32 out base (row 0 of this set), ld 1536, dup at +512
};

// Layer-1 sliced SpMM. Work = slice-major over (8 slices) x (A rows, B rows):
// the live table slice (<=4.5MB) stays XCD-L2-resident.
__global__ __launch_bounds__(256) void spmm1_sliced(S1Set A, S1Set B) {
  const int lane = threadIdx.x & 63;
  const int g = lane >> 3, k = lane & 7;
  int w = blockIdx.x * 4 + (threadIdx.x >> 6);
  const int step = gridDim.x * 4;
  const int per = A.nrows + B.nrows;
  const int total = 8 * per;
  for (; w < total; w += step) {
    int s = w / per;
    int rr = w - s * per;
    bool useA = rr < A.nrows;
    int r = useA ? rr : rr - A.nrows;
    int scol = s * 64;
    float acc[8] = {0.f, 0.f, 0.f, 0.f, 0.f, 0.f, 0.f, 0.f};
    gather_slice(useA ? A.s0 : B.s0, r, scol, lane, acc);
    gather_slice(useA ? A.s1 : B.s1, r, scol, lane, acc);
    if (!useA) gather_slice(B.s2, r, scol, lane, acc);
    reduce_groups(acc);
    #pragma unroll
    for (int i = 0; i < 8; i++) acc[i] = fmaxf(acc[i], 0.f);
    if (g == 0) {
      unsigned short* ebf = useA ? A.ebf : B.ebf;
      float* outp = useA ? A.outp : B.outp;
      uint4 o;
      o.x = (unsigned)f2bf(acc[0]) | ((unsigned)f2bf(acc[1]) << 16);
      o.y = (unsigned)f2bf(acc[2]) | ((unsigned)f2bf(acc[3]) << 16);
      o.z = (unsigned)f2bf(acc[4]) | ((unsigned)f2bf(acc[5]) << 16);
      o.w = (unsigned)f2bf(acc[6]) | ((unsigned)f2bf(acc[7]) << 16);
      *(uint4*)(ebf + (size_t)r * HDIM + scol + k * 8) = o;
      f32x4 v0 = {acc[0], acc[1], acc[2], acc[3]};
      f32x4 v1 = {acc[4], acc[5], acc[6], acc[7]};
      size_t base = (size_t)r * 1536 + scol + k * 8;
      __builtin_nontemporal_store(v0, (f32x4*)(outp + base));
      __builtin_nontemporal_store(v1, (f32x4*)(outp + base + 4));
      __builtin_nontemporal_store(v0, (f32x4*)(outp + base + 512));
      __builtin_nontemporal_store(v1, (f32x4*)(outp + base + 516));
    }
  }
}

struct SepSetS {
  int nrows, nseg;
  SSeg s0, s1, s2;           // tbl = 512-wide e matrices
  unsigned short* outp;      // bf16, ld ldo; seg s writes col slice s*512
  int ldo;
};

// Layers-2/3 sliced SpMM: per-segment independent gather; all 5 segments share
// the same e-table slices (4.5MB live), K-concat store.
__global__ __launch_bounds__(256) void spmm_sep_sliced(SepSetS A, SepSetS B) {
  const int lane = threadIdx.x & 63;
  const int g = lane >> 3, k = lane & 7;
  int w = blockIdx.x * 4 + (threadIdx.x >> 6);
  const int step = gridDim.x * 4;
  const int per = A.nrows + B.nrows;
  const int total = 8 * per;
  for (; w < total; w += step) {
    int s = w / per;
    int rr = w - s * per;
    bool useA = rr < A.nrows;
    int r = useA ? rr : rr - A.nrows;
    int scol = s * 64;
    unsigned short* outp = useA ? A.outp : B.outp;
    int ldo = useA ? A.ldo : B.ldo;
    int nseg = useA ? A.nseg : B.nseg;
    #pragma unroll
    for (int sidx = 0; sidx < 3; ++sidx) {
      if (sidx >= nseg) break;
      SSeg sg = (sidx == 0) ? (useA ? A.s0 : B.s0)
              : (sidx == 1) ? (useA ? A.s1 : B.s1)
                            : (useA ? A.s2 : B.s2);
      float acc[8] = {0.f, 0.f, 0.f, 0.f, 0.f, 0.f, 0.f, 0.f};
      gather_slice(sg, r, scol, lane, acc);
      reduce_groups(acc);
      if (g == 0) {
        uint4 o;
        o.x = (unsigned)f2bf(acc[0]) | ((unsigned)f2bf(acc[1]) << 16);
        o.y = (unsigned)f2bf(acc[2]) | ((unsigned)f2bf(acc[3]) << 16);
        o.z = (unsigned)f2bf(acc[4]) | ((unsigned)f2bf(acc[5]) << 16);
        o.w = (unsigned)f2bf(acc[6]) | ((unsigned)f2bf(acc[7]) << 16);
        *(uint4*)(outp + (size_t)r * ldo + sidx * HDIM + scol + k * 8) = o;
      }
    }
  }
}

// ---------- host ----------
extern "C" void kernel_launch(void* const* d_in, const int* in_sizes, int n_in,
                              void* d_out, int out_size, void* d_ws, size_t ws_size,
                              hipStream_t stream) {
  const float* feat0 = (const float*)d_in[0];
  const float* feat1 = (const float*)d_in[1];
  const int* a00_row = (const int*)d_in[2];
  const int* a00_col = (const int*)d_in[3];
  const float* a00_val = (const float*)d_in[4];
  const int* a01_row = (const int*)d_in[5];
  const int* a01_col = (const int*)d_in[6];
  const float* a01_val = (const float*)d_in[7];
  const int* a10_row = (const int*)d_in[8];
  const int* a10_col = (const int*)d_in[9];
  const float* a10_val = (const float*)d_in[10];
  const int* a11a_row = (const int*)d_in[11];
  const int* a11a_col = (const int*)d_in[12];
  const float* a11a_val = (const float*)d_in[13];
  const int* a11b_row = (const int*)d_in[14];
  const int* a11b_col = (const int*)d_in[15];
  const float* a11b_val = (const float*)d_in[16];

  const float *W1[5], *W2[5], *W3[5];  // order: 00, 01, 10, 11a, 11b
  if (in_sizes[18] == 512 * 512) {
    for (int r = 0; r < 5; r++) {
      W1[r] = (const float*)d_in[17 + 3 * r];
      W2[r] = (const float*)d_in[18 + 3 * r];
      W3[r] = (const float*)d_in[19 + 3 * r];
    }
  } else {
    for (int r = 0; r < 5; r++) {
      W1[r] = (const float*)d_in[17 + r];
      W2[r] = (const float*)d_in[22 + r];
      W3[r] = (const float*)d_in[27 + r];
    }
  }

  char* ws = (char*)d_ws;
  size_t off = 0;
  auto alloc = [&](size_t bytes) -> char* {
    char* p = ws + off;
    off += (bytes + 255) & ~(size_t)255;
    return p;
  };
  unsigned short* feat0b = (unsigned short*)alloc((size_t)N0 * FDIM * 2);  // reused as e2_0
  unsigned short* feat1b = (unsigned short*)alloc((size_t)N1 * FDIM * 2);  // reused as e2_1
  unsigned short* Wt1_0 = (unsigned short*)alloc((size_t)1024 * 1024 * 2);
  unsigned short* Wt1_1 = (unsigned short*)alloc((size_t)1536 * 1024 * 2);
  unsigned short* Wt2_0 = (unsigned short*)alloc((size_t)512 * 1024 * 2);
  unsigned short* Wt2_1 = (unsigned short*)alloc((size_t)512 * 1536 * 2);
  unsigned short* Wt3_0 = (unsigned short*)alloc((size_t)512 * 1024 * 2);
  unsigned short* Wt3_1 = (unsigned short*)alloc((size_t)512 * 1536 * 2);
  unsigned short* G0 = (unsigned short*)alloc((size_t)N0 * 1024 * 2);
  unsigned short* G1 = (unsigned short*)alloc((size_t)N1 * 1536 * 2);
  unsigned short* e0_0 = (unsigned short*)alloc((size_t)N0 * HDIM * 2);
  unsigned short* e0_1 = (unsigned short*)alloc((size_t)N1 * HDIM * 2);
  int* cur = (int*)alloc((size_t)(2 * N0 + 3 * N1) * 4);
  int* cur00 = cur;
  int* cur01 = cur + N0;
  int* cur10 = cur + 2 * N0;
  int* cur11a = cur + 2 * N0 + N1;
  int* cur11b = cur + 2 * N0 + 2 * N1;
  int* rp00 = (int*)alloc((N0 + 1) * 4);
  int* rp01 = (int*)alloc((N0 + 1) * 4);
  int* rp10 = (int*)alloc((N1 + 1) * 4);
  int* rp11a = (int*)alloc((N1 + 1) * 4);
  int* rp11b = (int*)alloc((N1 + 1) * 4);
  int* sc00 = (int*)alloc((size_t)E00 * 4);
  float* sv00 = (float*)alloc((size_t)E00 * 4);
  int* sc01 = (int*)alloc((size_t)E01 * 4);
  float* sv01 = (float*)alloc((size_t)E01 * 4);
  int* sc10 = (int*)alloc((size_t)E10 * 4);
  float* sv10 = (float*)alloc((size_t)E10 * 4);
  int* sc11a = (int*)alloc((size_t)E11A * 4);
  float* sv11a = (float*)alloc((size_t)E11A * 4);
  int* sc11b = (int*)alloc((size_t)E11B * 4);
  float* sv11b = (float*)alloc((size_t)E11B * 4);
  unsigned short* e2_0 = feat0b;
  unsigned short* e2_1 = feat1b;
  float* out = (float*)d_out;

  // --- conversions ---
  conv_bf16_kernel<<<(N0 * FDIM / 4 + 255) / 256, 256, 0, stream>>>(feat0, feat0b, N0 * FDIM / 4);
  conv_bf16_kernel<<<(N1 * FDIM / 4 + 255) / 256, 256, 0, stream>>>(feat1, feat1b, N1 * FDIM / 4);
  conv_weights_kernel<<<(2560 * 1024 + 255) / 256, 256, 0, stream>>>(W1[0], W1[2], W1[1], W1[3], W1[4], Wt1_0, Wt1_1, 1024);
  conv_wk_kernel<<<(512 * 2560 + 255) / 256, 256, 0, stream>>>(W2[0], W2[1], W2[2], W2[3], W2[4], Wt2_0, Wt2_1);
  conv_wk_kernel<<<(512 * 2560 + 255) / 256, 256, 0, stream>>>(W3[0], W3[1], W3[2], W3[3], W3[4], Wt3_0, Wt3_1);

  // --- CSR build ---
  int ncur = 2 * N0 + 3 * N1;
  zero_ints<<<(ncur + 255) / 256, 256, 0, stream>>>(cur, ncur);
  hist5<<<(NE_TOT + 255) / 256, 256, 0, stream>>>(a00_row, a01_row, a10_row, a11a_row, a11b_row,
                                                  cur00, cur01, cur10, cur11a, cur11b);
  scan5p<<<5, 1024, 0, stream>>>(cur00, rp00, cur01, rp01, cur10, rp10, cur11a, rp11a, cur11b, rp11b);
  scatter5<<<(NE_TOT + 255) / 256, 256, 0, stream>>>(
      a00_row, a00_col, a00_val, cur00, sc00, sv00,
      a01_row, a01_col, a01_val, cur01, sc01, sv01,
      a10_row, a10_col, a10_val, cur10, sc10, sv10,
      a11a_row, a11a_col, a11a_val, cur11a, sc11a, sv11a,
      a11b_row, a11b_col, a11b_val, cur11b, sc11b, sv11b);

  dim3 blk(256);
  int nbx0 = (N0 + BM - 1) / BM;   // 235
  int nbx1 = (N1 + BM - 1) / BM;   // 47
  const int SPMM_GRID = 2048;

  // --- Layer 1: GEMM-first, merged pair ---
  {
    GemmArgs ga = {feat0b, Wt1_0, G0, N0, 1024, 1024, nbx0, 1024, nbx0 * 8};
    GemmArgs gb = {feat1b, Wt1_1, G1, N1, 1536, 1024, nbx1, 1536, nbx1 * 12};
    gemm_pair<0><<<dim3(ga.nwg + gb.nwg), blk, 0, stream>>>(ga, gb);
  }
  {
    SSeg s00 = {rp00, sc00, sv00, G0, 1024};
    SSeg s01 = {rp01, sc01, sv01, G1, 1536};
    SSeg s10 = {rp10, sc10, sv10, G0 + 512, 1024};
    SSeg s11a = {rp11a, sc11a, sv11a, G1 + 512, 1536};
    SSeg s11b = {rp11b, sc11b, sv11b, G1 + 1024, 1536};
    S1Set A = {N0, 2, s00, s01, SSeg{}, e0_0, out};
    S1Set B = {N1, 3, s10, s11a, s11b, e0_1, out + (size_t)N0 * 1536};
    spmm1_sliced<<<dim3(SPMM_GRID), blk, 0, stream>>>(A, B);
  }

  // --- Layer 2: sliced SpMM-first (all segs share e0 slices), K-concat GEMM + relu ---
  {
    SSeg a0 = {rp00, sc00, sv00, e0_0, HDIM};
    SSeg a1 = {rp01, sc01, sv01, e0_1, HDIM};
    SSeg b0 = {rp10, sc10, sv10, e0_0, HDIM};
    SSeg b1 = {rp11a, sc11a, sv11a, e0_1, HDIM};
    SSeg b2 = {rp11b, sc11b, sv11b, e0_1, HDIM};
    SepSetS A = {N0, 2, a0, a1, SSeg{}, G0, 1024};
    SepSetS B = {N1, 3, b0, b1, b2, G1, 1536};
    spmm_sep_sliced<<<dim3(SPMM_GRID), blk, 0, stream>>>(A, B);
  }
  {
    GemmArgs ga = {G0, Wt2_0, e2_0, N0, 512, 1024, nbx0, 512, nbx0 * 4};
    GemmArgs gb = {G1, Wt2_1, e2_1, N1, 512, 1536, nbx1, 512, nbx1 * 4};
    gemm_pair<1><<<dim3(ga.nwg + gb.nwg), blk, 0, stream>>>(ga, gb);
  }

  // --- Layer 3: sliced SpMM-first; GEMM writes f32 NT straight into out cols [1024,1536) ---
  {
    SSeg a0 = {rp00, sc00, sv00, e2_0, HDIM};
    SSeg a1 = {rp01, sc01, sv01, e2_1, HDIM};
    SSeg b0 = {rp10, sc10, sv10, e2_0, HDIM};
    SSeg b1 = {rp11a, sc11a, sv11a, e2_1, HDIM};
    SSeg b2 = {rp11b, sc11b, sv11b, e2_1, HDIM};
    SepSetS A = {N0, 2, a0, a1, SSeg{}, G0, 1024};
    SepSetS B = {N1, 3, b0, b1, b2, G1, 1536};
    spmm_sep_sliced<<<dim3(SPMM_GRID), blk, 0, stream>>>(A, B);
  }
  {
    GemmArgs ga = {G0, Wt3_0, out + 1024, N0, 512, 1024, nbx0, 1536, nbx0 * 4};
    GemmArgs gb = {G1, Wt3_1, out + (size_t)N0 * 1536 + 1024, N1, 512, 1536, nbx1, 1536, nbx1 * 4};
    gemm_pair<2><<<dim3(ga.nwg + gb.nwg), blk, 0, stream>>>(ga, gb);
  }
}

// Round 7
// 1381.931 us; speedup vs baseline: 1.2394x; 1.2394x over previous
//
#include <hip/hip_runtime.h>
#include <stdint.h>

#define N0 30000
#define N1 6000
#define FDIM 1024
#define HDIM 512
#define E00 600000
#define E01 300000
#define E10 300000
#define E11A 400000
#define E11B 400000
#define NE_TOT (E00 + E01 + E10 + E11A + E11B)

typedef __attribute__((ext_vector_type(4))) float f32x4;
typedef __attribute__((ext_vector_type(8))) __bf16 bf16x8;

// ---------- helpers ----------
__device__ __forceinline__ unsigned short f2bf(float f) {
  unsigned u = __float_as_uint(f);
  u += 0x7fffu + ((u >> 16) & 1u);   // round-to-nearest-even
  return (unsigned short)(u >> 16);
}

__device__ __forceinline__ void gload16(const void* g, void* l) {
  __builtin_amdgcn_global_load_lds((const __attribute__((address_space(1))) void*)g,
                                   (__attribute__((address_space(3))) void*)l, 16, 0, 0);
}

// ---------- conversion kernels ----------
__global__ void conv_bf16_kernel(const float* __restrict__ src, unsigned short* __restrict__ dst, int n4) {
  int gid = blockIdx.x * blockDim.x + threadIdx.x;
  if (gid >= n4) return;
  float4 v = ((const float4*)src)[gid];
  ushort4 o;
  o.x = f2bf(v.x); o.y = f2bf(v.y); o.z = f2bf(v.z); o.w = f2bf(v.w);
  ((ushort4*)dst)[gid] = o;
}

// Layer-1 weights: N-stacked, Bt[n][k] (k = FDIM).
__global__ void conv_weights_kernel(const float* __restrict__ w00, const float* __restrict__ w10,
                                    const float* __restrict__ w01, const float* __restrict__ w11a,
                                    const float* __restrict__ w11b,
                                    unsigned short* __restrict__ dst0, unsigned short* __restrict__ dst1, int K) {
  int gid = blockIdx.x * blockDim.x + threadIdx.x;
  int total0 = 1024 * K;
  int total1 = 1536 * K;
  if (gid < total0) {
    int n = gid / K, k = gid - n * K;
    const float* w = (n < 512) ? w00 : w10;
    int nn = n & 511;
    dst0[gid] = f2bf(w[(size_t)k * 512 + nn]);
  } else if (gid < total0 + total1) {
    int g = gid - total0;
    int n = g / K, k = g - n * K;
    const float* w = (n < 512) ? w01 : ((n < 1024) ? w11a : w11b);
    int nn = n & 511;
    dst1[g] = f2bf(w[(size_t)k * 512 + nn]);
  }
}

// Layers-2/3 weights: K-stacked, Bt[n][k], n in [0,512).
__global__ void conv_wk_kernel(const float* __restrict__ w00, const float* __restrict__ w01,
                               const float* __restrict__ w10, const float* __restrict__ w11a,
                               const float* __restrict__ w11b,
                               unsigned short* __restrict__ dst0, unsigned short* __restrict__ dst1) {
  int gid = blockIdx.x * blockDim.x + threadIdx.x;
  const int T0 = 512 * 1024;
  const int T1 = 512 * 1536;
  if (gid < T0) {
    int n = gid >> 10, k = gid & 1023;
    const float* w = (k < 512) ? w00 : w01;
    dst0[gid] = f2bf(w[(size_t)(k & 511) * 512 + n]);
  } else if (gid < T0 + T1) {
    int g = gid - T0;
    int n = g / 1536, k = g - n * 1536;
    const float* w = (k < 512) ? w10 : ((k < 1024) ? w11a : w11b);
    dst1[g] = f2bf(w[(size_t)(k & 511) * 512 + n]);
  }
}

// ---------- CSR build ----------
__global__ void zero_ints(int* p, int n) {
  int g = blockIdx.x * blockDim.x + threadIdx.x;
  if (g < n) p[g] = 0;
}

__global__ void hist5(const int* __restrict__ r0, const int* __restrict__ r1, const int* __restrict__ r2,
                      const int* __restrict__ r3, const int* __restrict__ r4,
                      int* c0, int* c1, int* c2, int* c3, int* c4) {
  int g = blockIdx.x * blockDim.x + threadIdx.x;
  const int* r; int* c; int e;
  if (g < E00) { r = r0; c = c0; e = g; }
  else if (g < E00 + E01) { r = r1; c = c1; e = g - E00; }
  else if (g < E00 + E01 + E10) { r = r2; c = c2; e = g - (E00 + E01); }
  else if (g < E00 + E01 + E10 + E11A) { r = r3; c = c3; e = g - (E00 + E01 + E10); }
  else if (g < NE_TOT) { r = r4; c = c4; e = g - (E00 + E01 + E10 + E11A); }
  else return;
  atomicAdd(&c[r[e]], 1);
}

__global__ __launch_bounds__(1024) void scan5p(int* c0, int* rp0, int* c1, int* rp1,
                                               int* c2, int* rp2, int* c3, int* rp3,
                                               int* c4, int* rp4) {
  int b = blockIdx.x;
  int* cnt; int* rp; int n;
  if (b == 0) { cnt = c0; rp = rp0; n = N0; }
  else if (b == 1) { cnt = c1; rp = rp1; n = N0; }
  else if (b == 2) { cnt = c2; rp = rp2; n = N1; }
  else if (b == 3) { cnt = c3; rp = rp3; n = N1; }
  else { cnt = c4; rp = rp4; n = N1; }
  __shared__ int wsum[16];
  const int tid = threadIdx.x, lane = tid & 63, w = tid >> 6;
  int carry = 0;
  for (int base = 0; base < n; base += 1024) {
    int i = base + tid;
    int v = (i < n) ? cnt[i] : 0;
    int x = v;
    #pragma unroll
    for (int d = 1; d < 64; d <<= 1) {
      int y = __shfl_up(x, d, 64);
      if (lane >= d) x += y;
    }
    if (lane == 63) wsum[w] = x;
    __syncthreads();
    if (w == 0) {
      int t = (lane < 16) ? wsum[lane] : 0;
      #pragma unroll
      for (int d = 1; d < 16; d <<= 1) {
        int y = __shfl_up(t, d, 64);
        if (lane >= d) t += y;
      }
      if (lane < 16) wsum[lane] = t;
    }
    __syncthreads();
    int wpref = (w > 0) ? wsum[w - 1] : 0;
    int excl = carry + wpref + (x - v);
    if (i < n) { rp[i] = excl; cnt[i] = excl; }
    carry += wsum[15];
    __syncthreads();
  }
  if (tid == 0) rp[n] = carry;
}

__global__ void scatter5(const int* __restrict__ r0, const int* __restrict__ q0, const float* __restrict__ v0,
                         int* cur0, int* sc0, float* sv0,
                         const int* __restrict__ r1, const int* __restrict__ q1, const float* __restrict__ v1,
                         int* cur1, int* sc1, float* sv1,
                         const int* __restrict__ r2, const int* __restrict__ q2, const float* __restrict__ v2,
                         int* cur2, int* sc2, float* sv2,
                         const int* __restrict__ r3, const int* __restrict__ q3, const float* __restrict__ v3,
                         int* cur3, int* sc3, float* sv3,
                         const int* __restrict__ r4, const int* __restrict__ q4, const float* __restrict__ v4,
                         int* cur4, int* sc4, float* sv4) {
  int g = blockIdx.x * blockDim.x + threadIdx.x;
  const int* r; const int* q; const float* v; int* cur; int* sc; float* sv; int e;
  if (g < E00) { r = r0; q = q0; v = v0; cur = cur0; sc = sc0; sv = sv0; e = g; }
  else if (g < E00 + E01) { r = r1; q = q1; v = v1; cur = cur1; sc = sc1; sv = sv1; e = g - E00; }
  else if (g < E00 + E01 + E10) { r = r2; q = q2; v = v2; cur = cur2; sc = sc2; sv = sv2; e = g - (E00 + E01); }
  else if (g < E00 + E01 + E10 + E11A) { r = r3; q = q3; v = v3; cur = cur3; sc = sc3; sv = sv3; e = g - (E00 + E01 + E10); }
  else if (g < NE_TOT) { r = r4; q = q4; v = v4; cur = cur4; sc = sc4; sv = sv4; e = g - (E00 + E01 + E10 + E11A); }
  else return;
  int row = r[e];
  int p = atomicAdd(&cur[row], 1);
  sc[p] = q[e];
  sv[p] = v[e];
}

// ---------- bf16 MFMA GEMM: C = A[M][K] @ Bt[N][K]^T ----------
// MODE 0: bf16 store; MODE 1: bf16 + relu; MODE 2: f32 NT store (no relu).
#define BM 128
#define BN 128
#define BK 64

struct GemmArgs {
  const unsigned short* A;
  const unsigned short* Bt;
  void* C;
  int M, N, K, nbx, ldc, nwg;
};

template<int MODE>
__device__ __forceinline__ void gemm_body(const GemmArgs& g, int orig) {
  __shared__ unsigned short As[BM * BK];
  __shared__ unsigned short Bs[BN * BK];
  // bijective XCD-aware swizzle (m204) over the local sub-grid
  const int nwg = g.nwg;
  const int q = nwg >> 3, rr = nwg & 7;
  const int xcd = orig & 7, pos = orig >> 3;
  const int wg = (xcd < rr ? xcd * (q + 1) : rr * (q + 1) + (xcd - rr) * q) + pos;
  const int bx = wg % g.nbx;
  const int by = wg / g.nbx;

  const int tid = threadIdx.x;
  const int lane = tid & 63;
  const int wid = tid >> 6;
  const int m0 = bx * BM;
  const int n0 = by * BN;
  const int wm = (wid >> 1) * 64;
  const int wn = (wid & 1) * 64;
  const int M = g.M, K = g.K;

  f32x4 acc[4][4] = {};

  const int srow = wid * 32 + (lane >> 3);
  const int scol = (lane & 7) * 8;

  for (int k0 = 0; k0 < K; k0 += BK) {
    #pragma unroll
    for (int c = 0; c < 4; ++c) {
      int gr = m0 + srow + c * 8;
      if (gr > M - 1) gr = M - 1;
      gload16(g.A + (size_t)gr * K + k0 + scol, As + (wid * 32 + c * 8) * BK);
      int gn = n0 + srow + c * 8;
      gload16(g.Bt + (size_t)gn * K + k0 + scol, Bs + (wid * 32 + c * 8) * BK);
    }
    __syncthreads();
    #pragma unroll
    for (int ks = 0; ks < 2; ++ks) {
      bf16x8 af[4], bfr[4];
      #pragma unroll
      for (int i = 0; i < 4; i++)
        af[i] = *(const bf16x8*)(As + (wm + i * 16 + (lane & 15)) * BK + ks * 32 + (lane >> 4) * 8);
      #pragma unroll
      for (int j = 0; j < 4; j++)
        bfr[j] = *(const bf16x8*)(Bs + (wn + j * 16 + (lane & 15)) * BK + ks * 32 + (lane >> 4) * 8);
      #pragma unroll
      for (int i = 0; i < 4; i++)
        #pragma unroll
        for (int j = 0; j < 4; j++)
          acc[i][j] = __builtin_amdgcn_mfma_f32_16x16x32_bf16(af[i], bfr[j], acc[i][j], 0, 0, 0);
    }
    __syncthreads();
  }

  #pragma unroll
  for (int i = 0; i < 4; i++) {
    int rbase = m0 + wm + i * 16 + (lane >> 4) * 4;
    #pragma unroll
    for (int j = 0; j < 4; j++) {
      int col = n0 + wn + j * 16 + (lane & 15);
      #pragma unroll
      for (int r = 0; r < 4; r++) {
        int row = rbase + r;
        if (row < M) {
          float v = acc[i][j][r];
          if (MODE == 1) v = fmaxf(v, 0.f);
          if (MODE == 2)
            __builtin_nontemporal_store(v, &((float*)g.C)[(size_t)row * g.ldc + col]);
          else
            ((unsigned short*)g.C)[(size_t)row * g.ldc + col] = f2bf(v);
        }
      }
    }
  }
}

template<int MODE>
__global__ __launch_bounds__(256) void gemm_pair(GemmArgs ga, GemmArgs gb) {
  if ((int)blockIdx.x < ga.nwg) gemm_body<MODE>(ga, blockIdx.x);
  else gemm_body<MODE>(gb, blockIdx.x - ga.nwg);
}

// ---------- SpMM gather core ----------
__device__ __forceinline__ void acc8(float* acc, float v, const uint4& u) {
  acc[0] += v * __uint_as_float(u.x << 16);
  acc[1] += v * __uint_as_float(u.x & 0xffff0000u);
  acc[2] += v * __uint_as_float(u.y << 16);
  acc[3] += v * __uint_as_float(u.y & 0xffff0000u);
  acc[4] += v * __uint_as_float(u.z << 16);
  acc[5] += v * __uint_as_float(u.z & 0xffff0000u);
  acc[6] += v * __uint_as_float(u.w << 16);
  acc[7] += v * __uint_as_float(u.w & 0xffff0000u);
}

// Edge metadata (ci/cv) is read-once streaming: NT loads keep it from
// evicting gather-table lines out of L2.
__device__ __forceinline__ void gather_row(const int* __restrict__ ci, const float* __restrict__ cv,
                                           const unsigned short* __restrict__ gb, int ld,
                                           int e, int e1, float* acc) {
  for (; e + 7 < e1; e += 8) {
    int c0 = __builtin_nontemporal_load(ci + e);
    int c1 = __builtin_nontemporal_load(ci + e + 1);
    int c2 = __builtin_nontemporal_load(ci + e + 2);
    int c3 = __builtin_nontemporal_load(ci + e + 3);
    int c4 = __builtin_nontemporal_load(ci + e + 4);
    int c5 = __builtin_nontemporal_load(ci + e + 5);
    int c6 = __builtin_nontemporal_load(ci + e + 6);
    int c7 = __builtin_nontemporal_load(ci + e + 7);
    float v0 = __builtin_nontemporal_load(cv + e);
    float v1 = __builtin_nontemporal_load(cv + e + 1);
    float v2 = __builtin_nontemporal_load(cv + e + 2);
    float v3 = __builtin_nontemporal_load(cv + e + 3);
    float v4 = __builtin_nontemporal_load(cv + e + 4);
    float v5 = __builtin_nontemporal_load(cv + e + 5);
    float v6 = __builtin_nontemporal_load(cv + e + 6);
    float v7 = __builtin_nontemporal_load(cv + e + 7);
    uint4 u0 = *(const uint4*)(gb + (size_t)c0 * ld);
    uint4 u1 = *(const uint4*)(gb + (size_t)c1 * ld);
    uint4 u2 = *(const uint4*)(gb + (size_t)c2 * ld);
    uint4 u3 = *(const uint4*)(gb + (size_t)c3 * ld);
    uint4 u4 = *(const uint4*)(gb + (size_t)c4 * ld);
    uint4 u5 = *(const uint4*)(gb + (size_t)c5 * ld);
    uint4 u6 = *(const uint4*)(gb + (size_t)c6 * ld);
    uint4 u7 = *(const uint4*)(gb + (size_t)c7 * ld);
    acc8(acc, v0, u0); acc8(acc, v1, u1); acc8(acc, v2, u2); acc8(acc, v3, u3);
    acc8(acc, v4, u4); acc8(acc, v5, u5); acc8(acc, v6, u6); acc8(acc, v7, u7);
  }
  for (; e < e1; ++e) {
    int c = ci[e];
    float v = cv[e];
    uint4 u = *(const uint4*)(gb + (size_t)c * ld);
    acc8(acc, v, u);
  }
}

struct Seg {
  const int* rp; const int* ci; const float* cv;
  const unsigned short* tbl; int ld; int off;
};

__device__ __forceinline__ void gather_seg(const Seg& s, int r, int lane, float* acc) {
  int e = __builtin_amdgcn_readfirstlane(s.rp[r]);
  int e1 = __builtin_amdgcn_readfirstlane(s.rp[r + 1]);
  gather_row(s.ci, s.cv, s.tbl + s.off + lane * 8, s.ld, e, e1, acc);
}

struct Spmm1Set {
  int nrows, nseg;
  Seg s0, s1, s2;
  unsigned short* ebf;   // bf16 e0 (ld 512)
  float* outp;           // f32 out base (row 0 of this set), ld 1536, dup at +512
};

// Layer-1 merged SpMM (both node types in one launch, grid-stride persistent waves).
__global__ __launch_bounds__(256) void spmm1_pair(Spmm1Set A, Spmm1Set B) {
  const int lane = threadIdx.x & 63;
  const int gw = blockIdx.x * 4 + (threadIdx.x >> 6);
  const int W = gridDim.x * 4;
  const int total = A.nrows + B.nrows;
  for (int r0 = gw; r0 < total; r0 += W) {
    bool useA = (r0 < A.nrows);
    int r = useA ? r0 : r0 - A.nrows;
    float acc[8] = {0.f, 0.f, 0.f, 0.f, 0.f, 0.f, 0.f, 0.f};
    {
      Seg s = useA ? A.s0 : B.s0;
      gather_seg(s, r, lane, acc);
    }
    {
      Seg s = useA ? A.s1 : B.s1;
      gather_seg(s, r, lane, acc);
    }
    if (!useA) {
      gather_seg(B.s2, r, lane, acc);
    }
    #pragma unroll
    for (int i = 0; i < 8; i++) acc[i] = fmaxf(acc[i], 0.f);
    unsigned short* ebf = useA ? A.ebf : B.ebf;
    float* outp = useA ? A.outp : B.outp;
    uint4 o;
    o.x = (unsigned)f2bf(acc[0]) | ((unsigned)f2bf(acc[1]) << 16);
    o.y = (unsigned)f2bf(acc[2]) | ((unsigned)f2bf(acc[3]) << 16);
    o.z = (unsigned)f2bf(acc[4]) | ((unsigned)f2bf(acc[5]) << 16);
    o.w = (unsigned)f2bf(acc[6]) | ((unsigned)f2bf(acc[7]) << 16);
    *(uint4*)(ebf + (size_t)r * HDIM + lane * 8) = o;
    f32x4 v0 = {acc[0], acc[1], acc[2], acc[3]};
    f32x4 v1 = {acc[4], acc[5], acc[6], acc[7]};
    size_t base = (size_t)r * 1536 + lane * 8;
    __builtin_nontemporal_store(v0, (f32x4*)(outp + base));
    __builtin_nontemporal_store(v1, (f32x4*)(outp + base + 4));
    __builtin_nontemporal_store(v0, (f32x4*)(outp + base + 512));
    __builtin_nontemporal_store(v1, (f32x4*)(outp + base + 516));
  }
}

struct SepSet {
  int nrows, nseg;
  Seg s0, s1, s2;            // tbl = 512-wide e matrices, off 0, ld 512
  unsigned short* outp;      // bf16, ld_out; seg s writes col slice s*512
  int ldo;
};

// Layers-2/3 merged SpMM (per-segment independent gather, K-concat store).
__global__ __launch_bounds__(256) void spmm_sep_pair(SepSet A, SepSet B) {
  const int lane = threadIdx.x & 63;
  const int gw = blockIdx.x * 4 + (threadIdx.x >> 6);
  const int W = gridDim.x * 4;
  const int total = A.nrows + B.nrows;
  for (int r0 = gw; r0 < total; r0 += W) {
    bool useA = (r0 < A.nrows);
    int r = useA ? r0 : r0 - A.nrows;
    unsigned short* outp = useA ? A.outp : B.outp;
    int ldo = useA ? A.ldo : B.ldo;
    int nseg = useA ? A.nseg : B.nseg;
    #pragma unroll
    for (int sidx = 0; sidx < 3; ++sidx) {
      if (sidx >= nseg) break;
      Seg s = (sidx == 0) ? (useA ? A.s0 : B.s0)
            : (sidx == 1) ? (useA ? A.s1 : B.s1)
                          : (useA ? A.s2 : B.s2);
      float acc[8] = {0.f, 0.f, 0.f, 0.f, 0.f, 0.f, 0.f, 0.f};
      gather_seg(s, r, lane, acc);
      uint4 o;
      o.x = (unsigned)f2bf(acc[0]) | ((unsigned)f2bf(acc[1]) << 16);
      o.y = (unsigned)f2bf(acc[2]) | ((unsigned)f2bf(acc[3]) << 16);
      o.z = (unsigned)f2bf(acc[4]) | ((unsigned)f2bf(acc[5]) << 16);
      o.w = (unsigned)f2bf(acc[6]) | ((unsigned)f2bf(acc[7]) << 16);
      *(uint4*)(outp + (size_t)r * ldo + sidx * HDIM + lane * 8) = o;
    }
  }
}

// ---------- host ----------
extern "C" void kernel_launch(void* const* d_in, const int* in_sizes, int n_in,
                              void* d_out, int out_size, void* d_ws, size_t ws_size,
                              hipStream_t stream) {
  const float* feat0 = (const float*)d_in[0];
  const float* feat1 = (const float*)d_in[1];
  const int* a00_row = (const int*)d_in[2];
  const int* a00_col = (const int*)d_in[3];
  const float* a00_val = (const float*)d_in[4];
  const int* a01_row = (const int*)d_in[5];
  const int* a01_col = (const int*)d_in[6];
  const float* a01_val = (const float*)d_in[7];
  const int* a10_row = (const int*)d_in[8];
  const int* a10_col = (const int*)d_in[9];
  const float* a10_val = (const float*)d_in[10];
  const int* a11a_row = (const int*)d_in[11];
  const int* a11a_col = (const int*)d_in[12];
  const float* a11a_val = (const float*)d_in[13];
  const int* a11b_row = (const int*)d_in[14];
  const int* a11b_col = (const int*)d_in[15];
  const float* a11b_val = (const float*)d_in[16];

  const float *W1[5], *W2[5], *W3[5];  // order: 00, 01, 10, 11a, 11b
  if (in_sizes[18] == 512 * 512) {
    for (int r = 0; r < 5; r++) {
      W1[r] = (const float*)d_in[17 + 3 * r];
      W2[r] = (const float*)d_in[18 + 3 * r];
      W3[r] = (const float*)d_in[19 + 3 * r];
    }
  } else {
    for (int r = 0; r < 5; r++) {
      W1[r] = (const float*)d_in[17 + r];
      W2[r] = (const float*)d_in[22 + r];
      W3[r] = (const float*)d_in[27 + r];
    }
  }

  char* ws = (char*)d_ws;
  size_t off = 0;
  auto alloc = [&](size_t bytes) -> char* {
    char* p = ws + off;
    off += (bytes + 255) & ~(size_t)255;
    return p;
  };
  unsigned short* feat0b = (unsigned short*)alloc((size_t)N0 * FDIM * 2);  // reused as e2_0
  unsigned short* feat1b = (unsigned short*)alloc((size_t)N1 * FDIM * 2);  // reused as e2_1
  unsigned short* Wt1_0 = (unsigned short*)alloc((size_t)1024 * 1024 * 2);
  unsigned short* Wt1_1 = (unsigned short*)alloc((size_t)1536 * 1024 * 2);
  unsigned short* Wt2_0 = (unsigned short*)alloc((size_t)512 * 1024 * 2);
  unsigned short* Wt2_1 = (unsigned short*)alloc((size_t)512 * 1536 * 2);
  unsigned short* Wt3_0 = (unsigned short*)alloc((size_t)512 * 1024 * 2);
  unsigned short* Wt3_1 = (unsigned short*)alloc((size_t)512 * 1536 * 2);
  unsigned short* G0 = (unsigned short*)alloc((size_t)N0 * 1024 * 2);
  unsigned short* G1 = (unsigned short*)alloc((size_t)N1 * 1536 * 2);
  unsigned short* e0_0 = (unsigned short*)alloc((size_t)N0 * HDIM * 2);
  unsigned short* e0_1 = (unsigned short*)alloc((size_t)N1 * HDIM * 2);
  int* cur = (int*)alloc((size_t)(2 * N0 + 3 * N1) * 4);
  int* cur00 = cur;
  int* cur01 = cur + N0;
  int* cur10 = cur + 2 * N0;
  int* cur11a = cur + 2 * N0 + N1;
  int* cur11b = cur + 2 * N0 + 2 * N1;
  int* rp00 = (int*)alloc((N0 + 1) * 4);
  int* rp01 = (int*)alloc((N0 + 1) * 4);
  int* rp10 = (int*)alloc((N1 + 1) * 4);
  int* rp11a = (int*)alloc((N1 + 1) * 4);
  int* rp11b = (int*)alloc((N1 + 1) * 4);
  int* sc00 = (int*)alloc((size_t)E00 * 4);
  float* sv00 = (float*)alloc((size_t)E00 * 4);
  int* sc01 = (int*)alloc((size_t)E01 * 4);
  float* sv01 = (float*)alloc((size_t)E01 * 4);
  int* sc10 = (int*)alloc((size_t)E10 * 4);
  float* sv10 = (float*)alloc((size_t)E10 * 4);
  int* sc11a = (int*)alloc((size_t)E11A * 4);
  float* sv11a = (float*)alloc((size_t)E11A * 4);
  int* sc11b = (int*)alloc((size_t)E11B * 4);
  float* sv11b = (float*)alloc((size_t)E11B * 4);
  unsigned short* e2_0 = feat0b;
  unsigned short* e2_1 = feat1b;
  float* out = (float*)d_out;

  // --- conversions ---
  conv_bf16_kernel<<<(N0 * FDIM / 4 + 255) / 256, 256, 0, stream>>>(feat0, feat0b, N0 * FDIM / 4);
  conv_bf16_kernel<<<(N1 * FDIM / 4 + 255) / 256, 256, 0, stream>>>(feat1, feat1b, N1 * FDIM / 4);
  conv_weights_kernel<<<(2560 * 1024 + 255) / 256, 256, 0, stream>>>(W1[0], W1[2], W1[1], W1[3], W1[4], Wt1_0, Wt1_1, 1024);
  conv_wk_kernel<<<(512 * 2560 + 255) / 256, 256, 0, stream>>>(W2[0], W2[1], W2[2], W2[3], W2[4], Wt2_0, Wt2_1);
  conv_wk_kernel<<<(512 * 2560 + 255) / 256, 256, 0, stream>>>(W3[0], W3[1], W3[2], W3[3], W3[4], Wt3_0, Wt3_1);

  // --- CSR build ---
  int ncur = 2 * N0 + 3 * N1;
  zero_ints<<<(ncur + 255) / 256, 256, 0, stream>>>(cur, ncur);
  hist5<<<(NE_TOT + 255) / 256, 256, 0, stream>>>(a00_row, a01_row, a10_row, a11a_row, a11b_row,
                                                  cur00, cur01, cur10, cur11a, cur11b);
  scan5p<<<5, 1024, 0, stream>>>(cur00, rp00, cur01, rp01, cur10, rp10, cur11a, rp11a, cur11b, rp11b);
  scatter5<<<(NE_TOT + 255) / 256, 256, 0, stream>>>(
      a00_row, a00_col, a00_val, cur00, sc00, sv00,
      a01_row, a01_col, a01_val, cur01, sc01, sv01,
      a10_row, a10_col, a10_val, cur10, sc10, sv10,
      a11a_row, a11a_col, a11a_val, cur11a, sc11a, sv11a,
      a11b_row, a11b_col, a11b_val, cur11b, sc11b, sv11b);

  dim3 blk(256);
  int nbx0 = (N0 + BM - 1) / BM;   // 235
  int nbx1 = (N1 + BM - 1) / BM;   // 47
  const int SPMM_GRID = 2048;

  // Segments
  Seg sg00_G = {rp00, sc00, sv00, G0, 1024, 0};
  Seg sg01_G = {rp01, sc01, sv01, G1, 1536, 0};
  Seg sg10_G = {rp10, sc10, sv10, G0, 1024, 512};
  Seg sg11a_G = {rp11a, sc11a, sv11a, G1, 1536, 512};
  Seg sg11b_G = {rp11b, sc11b, sv11b, G1, 1536, 1024};

  // --- Layer 1: GEMM-first, merged pair ---
  {
    GemmArgs ga = {feat0b, Wt1_0, G0, N0, 1024, 1024, nbx0, 1024, nbx0 * 8};
    GemmArgs gb = {feat1b, Wt1_1, G1, N1, 1536, 1024, nbx1, 1536, nbx1 * 12};
    gemm_pair<0><<<dim3(ga.nwg + gb.nwg), blk, 0, stream>>>(ga, gb);
  }
  {
    Spmm1Set A = {N0, 2, sg00_G, sg01_G, Seg{}, e0_0, out};
    Spmm1Set B = {N1, 3, sg10_G, sg11a_G, sg11b_G, e0_1, out + (size_t)N0 * 1536};
    spmm1_pair<<<dim3(SPMM_GRID), blk, 0, stream>>>(A, B);
  }

  // --- Layer 2: SpMM-first (gather from 30/6 MB e0 tables), merged; K-concat GEMM + relu ---
  {
    Seg a0 = {rp00, sc00, sv00, e0_0, HDIM, 0};
    Seg a1 = {rp01, sc01, sv01, e0_1, HDIM, 0};
    Seg b0 = {rp10, sc10, sv10, e0_0, HDIM, 0};
    Seg b1 = {rp11a, sc11a, sv11a, e0_1, HDIM, 0};
    Seg b2 = {rp11b, sc11b, sv11b, e0_1, HDIM, 0};
    SepSet A = {N0, 2, a0, a1, Seg{}, G0, 1024};
    SepSet B = {N1, 3, b0, b1, b2, G1, 1536};
    spmm_sep_pair<<<dim3(SPMM_GRID), blk, 0, stream>>>(A, B);
  }
  {
    GemmArgs ga = {G0, Wt2_0, e2_0, N0, 512, 1024, nbx0, 512, nbx0 * 4};
    GemmArgs gb = {G1, Wt2_1, e2_1, N1, 512, 1536, nbx1, 512, nbx1 * 4};
    gemm_pair<1><<<dim3(ga.nwg + gb.nwg), blk, 0, stream>>>(ga, gb);
  }

  // --- Layer 3: SpMM-first, merged; GEMM writes f32 NT straight into out cols [1024,1536) ---
  {
    Seg a0 = {rp00, sc00, sv00, e2_0, HDIM, 0};
    Seg a1 = {rp01, sc01, sv01, e2_1, HDIM, 0};
    Seg b0 = {rp10, sc10, sv10, e2_0, HDIM, 0};
    Seg b1 = {rp11a, sc11a, sv11a, e2_1, HDIM, 0};
    Seg b2 = {rp11b, sc11b, sv11b, e2_1, HDIM, 0};
    SepSet A = {N0, 2, a0, a1, Seg{}, G0, 1024};
    SepSet B = {N1, 3, b0, b1, b2, G1, 1536};
    spmm_sep_pair<<<dim3(SPMM_GRID), blk, 0, stream>>>(A, B);
  }
  {
    GemmArgs ga = {G0, Wt3_0, out + 1024, N0, 512, 1024, nbx0, 1536, nbx0 * 4};
    GemmArgs gb = {G1, Wt3_1, out + (size_t)N0 * 1536 + 1024, N1, 512, 1536, nbx1, 1536, nbx1 * 4};
    gemm_pair<2><<<dim3(ga.nwg + gb.nwg), blk, 0, stream>>>(ga, gb);
  }
}

// Round 8
// 1329.461 us; speedup vs baseline: 1.2883x; 1.0395x over previous
//
#include <hip/hip_runtime.h>
#include <stdint.h>

#define N0 30000
#define N1 6000
#define N0PAD 30208
#define N1PAD 6144
#define FDIM 1024
#define HDIM 512
#define E00 600000
#define E01 300000
#define E10 300000
#define E11A 400000
#define E11B 400000
#define NE_TOT (E00 + E01 + E10 + E11A + E11B)

typedef __attribute__((ext_vector_type(4))) float f32x4;
typedef __attribute__((ext_vector_type(8))) __bf16 bf16x8;

// ---------- helpers ----------
__device__ __forceinline__ unsigned short f2bf(float f) {
  unsigned u = __float_as_uint(f);
  u += 0x7fffu + ((u >> 16) & 1u);   // round-to-nearest-even
  return (unsigned short)(u >> 16);
}

__device__ __forceinline__ void gload16(const void* g, void* l) {
  __builtin_amdgcn_global_load_lds((const __attribute__((address_space(1))) void*)g,
                                   (__attribute__((address_space(3))) void*)l, 16, 0, 0);
}

// ---------- conversion kernels ----------
__global__ void conv_bf16_kernel(const float* __restrict__ src, unsigned short* __restrict__ dst, int n4) {
  int gid = blockIdx.x * blockDim.x + threadIdx.x;
  if (gid >= n4) return;
  float4 v = ((const float4*)src)[gid];
  ushort4 o;
  o.x = f2bf(v.x); o.y = f2bf(v.y); o.z = f2bf(v.z); o.w = f2bf(v.w);
  ((ushort4*)dst)[gid] = o;
}

// Layer-1 weights: N-stacked, Bt[n][k] (k = FDIM).
__global__ void conv_weights_kernel(const float* __restrict__ w00, const float* __restrict__ w10,
                                    const float* __restrict__ w01, const float* __restrict__ w11a,
                                    const float* __restrict__ w11b,
                                    unsigned short* __restrict__ dst0, unsigned short* __restrict__ dst1, int K) {
  int gid = blockIdx.x * blockDim.x + threadIdx.x;
  int total0 = 1024 * K;
  int total1 = 1536 * K;
  if (gid < total0) {
    int n = gid / K, k = gid - n * K;
    const float* w = (n < 512) ? w00 : w10;
    int nn = n & 511;
    dst0[gid] = f2bf(w[(size_t)k * 512 + nn]);
  } else if (gid < total0 + total1) {
    int g = gid - total0;
    int n = g / K, k = g - n * K;
    const float* w = (n < 512) ? w01 : ((n < 1024) ? w11a : w11b);
    int nn = n & 511;
    dst1[g] = f2bf(w[(size_t)k * 512 + nn]);
  }
}

// Layers-2/3 weights: K-stacked, Bt[n][k], n in [0,512).
__global__ void conv_wk_kernel(const float* __restrict__ w00, const float* __restrict__ w01,
                               const float* __restrict__ w10, const float* __restrict__ w11a,
                               const float* __restrict__ w11b,
                               unsigned short* __restrict__ dst0, unsigned short* __restrict__ dst1) {
  int gid = blockIdx.x * blockDim.x + threadIdx.x;
  const int T0 = 512 * 1024;
  const int T1 = 512 * 1536;
  if (gid < T0) {
    int n = gid >> 10, k = gid & 1023;
    const float* w = (k < 512) ? w00 : w01;
    dst0[gid] = f2bf(w[(size_t)(k & 511) * 512 + n]);
  } else if (gid < T0 + T1) {
    int g = gid - T0;
    int n = g / 1536, k = g - n * 1536;
    const float* w = (k < 512) ? w10 : ((k < 1024) ? w11a : w11b);
    dst1[g] = f2bf(w[(size_t)(k & 511) * 512 + n]);
  }
}

// ---------- CSR build ----------
__global__ void zero_ints(int* p, int n) {
  int g = blockIdx.x * blockDim.x + threadIdx.x;
  if (g < n) p[g] = 0;
}

__global__ void hist5(const int* __restrict__ r0, const int* __restrict__ r1, const int* __restrict__ r2,
                      const int* __restrict__ r3, const int* __restrict__ r4,
                      int* c0, int* c1, int* c2, int* c3, int* c4) {
  int g = blockIdx.x * blockDim.x + threadIdx.x;
  const int* r; int* c; int e;
  if (g < E00) { r = r0; c = c0; e = g; }
  else if (g < E00 + E01) { r = r1; c = c1; e = g - E00; }
  else if (g < E00 + E01 + E10) { r = r2; c = c2; e = g - (E00 + E01); }
  else if (g < E00 + E01 + E10 + E11A) { r = r3; c = c3; e = g - (E00 + E01 + E10); }
  else if (g < NE_TOT) { r = r4; c = c4; e = g - (E00 + E01 + E10 + E11A); }
  else return;
  atomicAdd(&c[r[e]], 1);
}

__global__ __launch_bounds__(1024) void scan5p(int* c0, int* rp0, int* c1, int* rp1,
                                               int* c2, int* rp2, int* c3, int* rp3,
                                               int* c4, int* rp4) {
  int b = blockIdx.x;
  int* cnt; int* rp; int n;
  if (b == 0) { cnt = c0; rp = rp0; n = N0; }
  else if (b == 1) { cnt = c1; rp = rp1; n = N0; }
  else if (b == 2) { cnt = c2; rp = rp2; n = N1; }
  else if (b == 3) { cnt = c3; rp = rp3; n = N1; }
  else { cnt = c4; rp = rp4; n = N1; }
  __shared__ int wsum[16];
  const int tid = threadIdx.x, lane = tid & 63, w = tid >> 6;
  int carry = 0;
  for (int base = 0; base < n; base += 1024) {
    int i = base + tid;
    int v = (i < n) ? cnt[i] : 0;
    int x = v;
    #pragma unroll
    for (int d = 1; d < 64; d <<= 1) {
      int y = __shfl_up(x, d, 64);
      if (lane >= d) x += y;
    }
    if (lane == 63) wsum[w] = x;
    __syncthreads();
    if (w == 0) {
      int t = (lane < 16) ? wsum[lane] : 0;
      #pragma unroll
      for (int d = 1; d < 16; d <<= 1) {
        int y = __shfl_up(t, d, 64);
        if (lane >= d) t += y;
      }
      if (lane < 16) wsum[lane] = t;
    }
    __syncthreads();
    int wpref = (w > 0) ? wsum[w - 1] : 0;
    int excl = carry + wpref + (x - v);
    if (i < n) { rp[i] = excl; cnt[i] = excl; }
    carry += wsum[15];
    __syncthreads();
  }
  if (tid == 0) rp[n] = carry;
}

__global__ void scatter5(const int* __restrict__ r0, const int* __restrict__ q0, const float* __restrict__ v0,
                         int* cur0, int* sc0, float* sv0,
                         const int* __restrict__ r1, const int* __restrict__ q1, const float* __restrict__ v1,
                         int* cur1, int* sc1, float* sv1,
                         const int* __restrict__ r2, const int* __restrict__ q2, const float* __restrict__ v2,
                         int* cur2, int* sc2, float* sv2,
                         const int* __restrict__ r3, const int* __restrict__ q3, const float* __restrict__ v3,
                         int* cur3, int* sc3, float* sv3,
                         const int* __restrict__ r4, const int* __restrict__ q4, const float* __restrict__ v4,
                         int* cur4, int* sc4, float* sv4) {
  int g = blockIdx.x * blockDim.x + threadIdx.x;
  const int* r; const int* q; const float* v; int* cur; int* sc; float* sv; int e;
  if (g < E00) { r = r0; q = q0; v = v0; cur = cur0; sc = sc0; sv = sv0; e = g; }
  else if (g < E00 + E01) { r = r1; q = q1; v = v1; cur = cur1; sc = sc1; sv = sv1; e = g - E00; }
  else if (g < E00 + E01 + E10) { r = r2; q = q2; v = v2; cur = cur2; sc = sc2; sv = sv2; e = g - (E00 + E01); }
  else if (g < E00 + E01 + E10 + E11A) { r = r3; q = q3; v = v3; cur = cur3; sc = sc3; sv = sv3; e = g - (E00 + E01 + E10); }
  else if (g < NE_TOT) { r = r4; q = q4; v = v4; cur = cur4; sc = sc4; sv = sv4; e = g - (E00 + E01 + E10 + E11A); }
  else return;
  int row = r[e];
  int p = atomicAdd(&cur[row], 1);
  sc[p] = q[e];
  sv[p] = v[e];
}

// ---------- 256x256 pipelined bf16 MFMA GEMM: C = A[M][K] @ Bt[N][K]^T ----------
// 8 waves (2M x 4N), BK=64, double-buffered 128KB LDS, counted vmcnt, st-swizzle.
// MODE 0: bf16 store; MODE 1: bf16 + relu; MODE 2: f32 NT store (no relu).
struct GemmArgs {
  const unsigned short* A;
  const unsigned short* Bt;
  void* C;
  int M, N, K, nbx, ldc, nwg;
};

template<int MODE>
__device__ __forceinline__ void gemm256_body(const GemmArgs& g, int orig) {
  __shared__ unsigned short lds[65536];  // 128 KB: buf b at b*32768 (A 16384 | B 16384)
  // bijective XCD-aware swizzle (m204) over the local sub-grid
  const int nwg = g.nwg;
  const int q = nwg >> 3, rr = nwg & 7;
  const int xcd = orig & 7, pos = orig >> 3;
  const int wg = (xcd < rr ? xcd * (q + 1) : rr * (q + 1) + (xcd - rr) * q) + pos;
  const int bx = wg % g.nbx;
  const int by = wg / g.nbx;

  const int tid = threadIdx.x;
  const int lane = tid & 63;
  const int wid = tid >> 6;     // 0..7
  const int wr = wid >> 2;      // 0..1  (M half)
  const int wc = wid & 3;       // 0..3  (N quarter)
  const int m0 = bx * 256;
  const int n0 = by * 256;
  const int K = g.K;
  const int nt = K >> 6;
  const int lo16 = lane & 15;
  const int hi = lane >> 4;

  f32x4 acc[8][4] = {};

  // Staging geometry: tile = 16384 shorts; thread t covers 4 chunks of 8 shorts.
  // LDS stays LINEAR; the st-swizzle is applied by pre-swizzling the GLOBAL col
  // (rule #21: gload_lds writes base+lane*16 only).
  int srow[4], scol[4];
  #pragma unroll
  for (int i = 0; i < 4; i++) {
    int o = i * 4096 + tid * 8;          // short offset in tile
    int row = o >> 6;                    // 64 shorts per row
    int c8 = (o >> 3) & 7;               // 8-short group within row
    srow[i] = row;
    scol[i] = ((c8 ^ (row & 7)) * 8);    // pre-swizzled global col (shorts)
  }

  auto stage = [&](int kt, int b) {
    const unsigned short* Agl = g.A + (size_t)m0 * K + kt * 64;
    const unsigned short* Bgl = g.Bt + (size_t)n0 * K + kt * 64;
    unsigned short* Al = lds + b * 32768;
    unsigned short* Bl = Al + 16384;
    #pragma unroll
    for (int i = 0; i < 4; i++)
      gload16(Agl + (size_t)srow[i] * K + scol[i], Al + i * 4096 + tid * 8);
    #pragma unroll
    for (int i = 0; i < 4; i++)
      gload16(Bgl + (size_t)srow[i] * K + scol[i], Bl + i * 4096 + tid * 8);
  };

  // prologue: tiles 0 and 1 in flight; wait for tile 0 (8 of tile 1 outstanding)
  stage(0, 0);
  stage(1, 1);
  asm volatile("s_waitcnt vmcnt(8)" ::: "memory");
  __builtin_amdgcn_s_barrier();
  __builtin_amdgcn_sched_barrier(0);

  for (int t = 0; t < nt; ++t) {
    const int cur = t & 1;
    const unsigned short* Ab = lds + cur * 32768;
    const unsigned short* Bb = Ab + 16384;

    bf16x8 bfr[4][2];
    #pragma unroll
    for (int n = 0; n < 4; n++)
      #pragma unroll
      for (int ks = 0; ks < 2; ks++) {
        int row = wc * 64 + n * 16 + lo16;
        int c8 = (ks * 4 + hi) ^ (row & 7);
        bfr[n][ks] = *(const bf16x8*)(Bb + row * 64 + c8 * 8);
      }
    #pragma unroll
    for (int h = 0; h < 2; h++) {
      bf16x8 af[4][2];
      #pragma unroll
      for (int m = 0; m < 4; m++)
        #pragma unroll
        for (int ks = 0; ks < 2; ks++) {
          int row = wr * 128 + (h * 4 + m) * 16 + lo16;
          int c8 = (ks * 4 + hi) ^ (row & 7);
          af[m][ks] = *(const bf16x8*)(Ab + row * 64 + c8 * 8);
        }
      if (h == 1) {
        // all ds_reads of buf[cur] complete chip-visible -> safe to overwrite
        asm volatile("s_waitcnt lgkmcnt(0)" ::: "memory");
        __builtin_amdgcn_sched_barrier(0);
        __builtin_amdgcn_s_barrier();
        __builtin_amdgcn_sched_barrier(0);
        if (t + 2 < nt) stage(t + 2, cur);
      }
      __builtin_amdgcn_s_setprio(1);
      #pragma unroll
      for (int m = 0; m < 4; m++)
        #pragma unroll
        for (int n = 0; n < 4; n++)
          #pragma unroll
          for (int ks = 0; ks < 2; ks++)
            acc[h * 4 + m][n] = __builtin_amdgcn_mfma_f32_16x16x32_bf16(
                af[m][ks], bfr[n][ks], acc[h * 4 + m][n], 0, 0, 0);
      __builtin_amdgcn_s_setprio(0);
    }
    // counted wait: tile t+1's 8 loads arrived (t+2's 8 stay in flight)
    if (t + 2 < nt) {
      asm volatile("s_waitcnt vmcnt(8)" ::: "memory");
    } else if (t + 1 < nt) {
      asm volatile("s_waitcnt vmcnt(0)" ::: "memory");
    }
    __builtin_amdgcn_s_barrier();
    __builtin_amdgcn_sched_barrier(0);
  }

  #pragma unroll
  for (int i = 0; i < 8; i++) {
    int rbase = m0 + wr * 128 + i * 16 + hi * 4;
    #pragma unroll
    for (int j = 0; j < 4; j++) {
      int col = n0 + wc * 64 + j * 16 + lo16;
      #pragma unroll
      for (int r = 0; r < 4; r++) {
        int row = rbase + r;
        if (row < g.M) {
          float v = acc[i][j][r];
          if (MODE == 1) v = fmaxf(v, 0.f);
          if (MODE == 2)
            __builtin_nontemporal_store(v, &((float*)g.C)[(size_t)row * g.ldc + col]);
          else
            ((unsigned short*)g.C)[(size_t)row * g.ldc + col] = f2bf(v);
        }
      }
    }
  }
}

template<int MODE>
__global__ __launch_bounds__(512, 2) void gemm_pair(GemmArgs ga, GemmArgs gb) {
  if ((int)blockIdx.x < ga.nwg) gemm256_body<MODE>(ga, blockIdx.x);
  else gemm256_body<MODE>(gb, blockIdx.x - ga.nwg);
}

// ---------- SpMM gather core ----------
__device__ __forceinline__ void acc8(float* acc, float v, const uint4& u) {
  acc[0] += v * __uint_as_float(u.x << 16);
  acc[1] += v * __uint_as_float(u.x & 0xffff0000u);
  acc[2] += v * __uint_as_float(u.y << 16);
  acc[3] += v * __uint_as_float(u.y & 0xffff0000u);
  acc[4] += v * __uint_as_float(u.z << 16);
  acc[5] += v * __uint_as_float(u.z & 0xffff0000u);
  acc[6] += v * __uint_as_float(u.w << 16);
  acc[7] += v * __uint_as_float(u.w & 0xffff0000u);
}

__device__ __forceinline__ void gather_row(const int* __restrict__ ci, const float* __restrict__ cv,
                                           const unsigned short* __restrict__ gb, int ld,
                                           int e, int e1, float* acc) {
  for (; e + 7 < e1; e += 8) {
    int c0 = ci[e], c1 = ci[e + 1], c2 = ci[e + 2], c3 = ci[e + 3];
    int c4 = ci[e + 4], c5 = ci[e + 5], c6 = ci[e + 6], c7 = ci[e + 7];
    float v0 = cv[e], v1 = cv[e + 1], v2 = cv[e + 2], v3 = cv[e + 3];
    float v4 = cv[e + 4], v5 = cv[e + 5], v6 = cv[e + 6], v7 = cv[e + 7];
    uint4 u0 = *(const uint4*)(gb + (size_t)c0 * ld);
    uint4 u1 = *(const uint4*)(gb + (size_t)c1 * ld);
    uint4 u2 = *(const uint4*)(gb + (size_t)c2 * ld);
    uint4 u3 = *(const uint4*)(gb + (size_t)c3 * ld);
    uint4 u4 = *(const uint4*)(gb + (size_t)c4 * ld);
    uint4 u5 = *(const uint4*)(gb + (size_t)c5 * ld);
    uint4 u6 = *(const uint4*)(gb + (size_t)c6 * ld);
    uint4 u7 = *(const uint4*)(gb + (size_t)c7 * ld);
    acc8(acc, v0, u0); acc8(acc, v1, u1); acc8(acc, v2, u2); acc8(acc, v3, u3);
    acc8(acc, v4, u4); acc8(acc, v5, u5); acc8(acc, v6, u6); acc8(acc, v7, u7);
  }
  for (; e < e1; ++e) {
    int c = ci[e];
    float v = cv[e];
    uint4 u = *(const uint4*)(gb + (size_t)c * ld);
    acc8(acc, v, u);
  }
}

struct Seg {
  const int* rp; const int* ci; const float* cv;
  const unsigned short* tbl; int ld; int off;
};

__device__ __forceinline__ void gather_seg(const Seg& s, int r, int lane, float* acc) {
  int e = __builtin_amdgcn_readfirstlane(s.rp[r]);
  int e1 = __builtin_amdgcn_readfirstlane(s.rp[r + 1]);
  gather_row(s.ci, s.cv, s.tbl + s.off + lane * 8, s.ld, e, e1, acc);
}

struct Spmm1Set {
  int nrows, nseg;
  Seg s0, s1, s2;
  unsigned short* ebf;   // bf16 e0 (ld 512)
  float* outp;           // f32 out base (row 0 of this set), ld 1536, dup at +512
};

__global__ __launch_bounds__(256) void spmm1_pair(Spmm1Set A, Spmm1Set B) {
  const int lane = threadIdx.x & 63;
  const int gw = blockIdx.x * 4 + (threadIdx.x >> 6);
  const int W = gridDim.x * 4;
  const int total = A.nrows + B.nrows;
  for (int r0 = gw; r0 < total; r0 += W) {
    bool useA = (r0 < A.nrows);
    int r = useA ? r0 : r0 - A.nrows;
    float acc[8] = {0.f, 0.f, 0.f, 0.f, 0.f, 0.f, 0.f, 0.f};
    {
      Seg s = useA ? A.s0 : B.s0;
      gather_seg(s, r, lane, acc);
    }
    {
      Seg s = useA ? A.s1 : B.s1;
      gather_seg(s, r, lane, acc);
    }
    if (!useA) {
      gather_seg(B.s2, r, lane, acc);
    }
    #pragma unroll
    for (int i = 0; i < 8; i++) acc[i] = fmaxf(acc[i], 0.f);
    unsigned short* ebf = useA ? A.ebf : B.ebf;
    float* outp = useA ? A.outp : B.outp;
    uint4 o;
    o.x = (unsigned)f2bf(acc[0]) | ((unsigned)f2bf(acc[1]) << 16);
    o.y = (unsigned)f2bf(acc[2]) | ((unsigned)f2bf(acc[3]) << 16);
    o.z = (unsigned)f2bf(acc[4]) | ((unsigned)f2bf(acc[5]) << 16);
    o.w = (unsigned)f2bf(acc[6]) | ((unsigned)f2bf(acc[7]) << 16);
    *(uint4*)(ebf + (size_t)r * HDIM + lane * 8) = o;
    f32x4 v0 = {acc[0], acc[1], acc[2], acc[3]};
    f32x4 v1 = {acc[4], acc[5], acc[6], acc[7]};
    size_t base = (size_t)r * 1536 + lane * 8;
    __builtin_nontemporal_store(v0, (f32x4*)(outp + base));
    __builtin_nontemporal_store(v1, (f32x4*)(outp + base + 4));
    __builtin_nontemporal_store(v0, (f32x4*)(outp + base + 512));
    __builtin_nontemporal_store(v1, (f32x4*)(outp + base + 516));
  }
}

struct SepSet {
  int nrows, nseg;
  Seg s0, s1, s2;            // tbl = 512-wide e matrices, off 0, ld 512
  unsigned short* outp;      // bf16, ld_out; seg s writes col slice s*512
  int ldo;
};

__global__ __launch_bounds__(256) void spmm_sep_pair(SepSet A, SepSet B) {
  const int lane = threadIdx.x & 63;
  const int gw = blockIdx.x * 4 + (threadIdx.x >> 6);
  const int W = gridDim.x * 4;
  const int total = A.nrows + B.nrows;
  for (int r0 = gw; r0 < total; r0 += W) {
    bool useA = (r0 < A.nrows);
    int r = useA ? r0 : r0 - A.nrows;
    unsigned short* outp = useA ? A.outp : B.outp;
    int ldo = useA ? A.ldo : B.ldo;
    int nseg = useA ? A.nseg : B.nseg;
    #pragma unroll
    for (int sidx = 0; sidx < 3; ++sidx) {
      if (sidx >= nseg) break;
      Seg s = (sidx == 0) ? (useA ? A.s0 : B.s0)
            : (sidx == 1) ? (useA ? A.s1 : B.s1)
                          : (useA ? A.s2 : B.s2);
      float acc[8] = {0.f, 0.f, 0.f, 0.f, 0.f, 0.f, 0.f, 0.f};
      gather_seg(s, r, lane, acc);
      uint4 o;
      o.x = (unsigned)f2bf(acc[0]) | ((unsigned)f2bf(acc[1]) << 16);
      o.y = (unsigned)f2bf(acc[2]) | ((unsigned)f2bf(acc[3]) << 16);
      o.z = (unsigned)f2bf(acc[4]) | ((unsigned)f2bf(acc[5]) << 16);
      o.w = (unsigned)f2bf(acc[6]) | ((unsigned)f2bf(acc[7]) << 16);
      *(uint4*)(outp + (size_t)r * ldo + sidx * HDIM + lane * 8) = o;
    }
  }
}

// ---------- host ----------
extern "C" void kernel_launch(void* const* d_in, const int* in_sizes, int n_in,
                              void* d_out, int out_size, void* d_ws, size_t ws_size,
                              hipStream_t stream) {
  const float* feat0 = (const float*)d_in[0];
  const float* feat1 = (const float*)d_in[1];
  const int* a00_row = (const int*)d_in[2];
  const int* a00_col = (const int*)d_in[3];
  const float* a00_val = (const float*)d_in[4];
  const int* a01_row = (const int*)d_in[5];
  const int* a01_col = (const int*)d_in[6];
  const float* a01_val = (const float*)d_in[7];
  const int* a10_row = (const int*)d_in[8];
  const int* a10_col = (const int*)d_in[9];
  const float* a10_val = (const float*)d_in[10];
  const int* a11a_row = (const int*)d_in[11];
  const int* a11a_col = (const int*)d_in[12];
  const float* a11a_val = (const float*)d_in[13];
  const int* a11b_row = (const int*)d_in[14];
  const int* a11b_col = (const int*)d_in[15];
  const float* a11b_val = (const float*)d_in[16];

  const float *W1[5], *W2[5], *W3[5];  // order: 00, 01, 10, 11a, 11b
  if (in_sizes[18] == 512 * 512) {
    for (int r = 0; r < 5; r++) {
      W1[r] = (const float*)d_in[17 + 3 * r];
      W2[r] = (const float*)d_in[18 + 3 * r];
      W3[r] = (const float*)d_in[19 + 3 * r];
    }
  } else {
    for (int r = 0; r < 5; r++) {
      W1[r] = (const float*)d_in[17 + r];
      W2[r] = (const float*)d_in[22 + r];
      W3[r] = (const float*)d_in[27 + r];
    }
  }

  char* ws = (char*)d_ws;
  size_t off = 0;
  auto alloc = [&](size_t bytes) -> char* {
    char* p = ws + off;
    off += (bytes + 255) & ~(size_t)255;
    return p;
  };
  // M-padded allocations (GEMM A-reads go up to N0PAD/N1PAD rows; stores guarded)
  unsigned short* feat0b = (unsigned short*)alloc((size_t)N0PAD * FDIM * 2);  // reused as e2_0
  unsigned short* feat1b = (unsigned short*)alloc((size_t)N1PAD * FDIM * 2);  // reused as e2_1
  unsigned short* Wt1_0 = (unsigned short*)alloc((size_t)1024 * 1024 * 2);
  unsigned short* Wt1_1 = (unsigned short*)alloc((size_t)1536 * 1024 * 2);
  unsigned short* Wt2_0 = (unsigned short*)alloc((size_t)512 * 1024 * 2);
  unsigned short* Wt2_1 = (unsigned short*)alloc((size_t)512 * 1536 * 2);
  unsigned short* Wt3_0 = (unsigned short*)alloc((size_t)512 * 1024 * 2);
  unsigned short* Wt3_1 = (unsigned short*)alloc((size_t)512 * 1536 * 2);
  unsigned short* G0 = (unsigned short*)alloc((size_t)N0PAD * 1024 * 2);
  unsigned short* G1 = (unsigned short*)alloc((size_t)N1PAD * 1536 * 2);
  unsigned short* e0_0 = (unsigned short*)alloc((size_t)N0 * HDIM * 2);
  unsigned short* e0_1 = (unsigned short*)alloc((size_t)N1 * HDIM * 2);
  int* cur = (int*)alloc((size_t)(2 * N0 + 3 * N1) * 4);
  int* cur00 = cur;
  int* cur01 = cur + N0;
  int* cur10 = cur + 2 * N0;
  int* cur11a = cur + 2 * N0 + N1;
  int* cur11b = cur + 2 * N0 + 2 * N1;
  int* rp00 = (int*)alloc((N0 + 1) * 4);
  int* rp01 = (int*)alloc((N0 + 1) * 4);
  int* rp10 = (int*)alloc((N1 + 1) * 4);
  int* rp11a = (int*)alloc((N1 + 1) * 4);
  int* rp11b = (int*)alloc((N1 + 1) * 4);
  int* sc00 = (int*)alloc((size_t)E00 * 4);
  float* sv00 = (float*)alloc((size_t)E00 * 4);
  int* sc01 = (int*)alloc((size_t)E01 * 4);
  float* sv01 = (float*)alloc((size_t)E01 * 4);
  int* sc10 = (int*)alloc((size_t)E10 * 4);
  float* sv10 = (float*)alloc((size_t)E10 * 4);
  int* sc11a = (int*)alloc((size_t)E11A * 4);
  float* sv11a = (float*)alloc((size_t)E11A * 4);
  int* sc11b = (int*)alloc((size_t)E11B * 4);
  float* sv11b = (float*)alloc((size_t)E11B * 4);
  unsigned short* e2_0 = feat0b;
  unsigned short* e2_1 = feat1b;
  float* out = (float*)d_out;

  // --- conversions ---
  conv_bf16_kernel<<<(N0 * FDIM / 4 + 255) / 256, 256, 0, stream>>>(feat0, feat0b, N0 * FDIM / 4);
  conv_bf16_kernel<<<(N1 * FDIM / 4 + 255) / 256, 256, 0, stream>>>(feat1, feat1b, N1 * FDIM / 4);
  conv_weights_kernel<<<(2560 * 1024 + 255) / 256, 256, 0, stream>>>(W1[0], W1[2], W1[1], W1[3], W1[4], Wt1_0, Wt1_1, 1024);
  conv_wk_kernel<<<(512 * 2560 + 255) / 256, 256, 0, stream>>>(W2[0], W2[1], W2[2], W2[3], W2[4], Wt2_0, Wt2_1);
  conv_wk_kernel<<<(512 * 2560 + 255) / 256, 256, 0, stream>>>(W3[0], W3[1], W3[2], W3[3], W3[4], Wt3_0, Wt3_1);

  // --- CSR build ---
  int ncur = 2 * N0 + 3 * N1;
  zero_ints<<<(ncur + 255) / 256, 256, 0, stream>>>(cur, ncur);
  hist5<<<(NE_TOT + 255) / 256, 256, 0, stream>>>(a00_row, a01_row, a10_row, a11a_row, a11b_row,
                                                  cur00, cur01, cur10, cur11a, cur11b);
  scan5p<<<5, 1024, 0, stream>>>(cur00, rp00, cur01, rp01, cur10, rp10, cur11a, rp11a, cur11b, rp11b);
  scatter5<<<(NE_TOT + 255) / 256, 256, 0, stream>>>(
      a00_row, a00_col, a00_val, cur00, sc00, sv00,
      a01_row, a01_col, a01_val, cur01, sc01, sv01,
      a10_row, a10_col, a10_val, cur10, sc10, sv10,
      a11a_row, a11a_col, a11a_val, cur11a, sc11a, sv11a,
      a11b_row, a11b_col, a11b_val, cur11b, sc11b, sv11b);

  dim3 blk512(512);
  dim3 blk(256);
  int nbx0 = N0PAD / 256;   // 118
  int nbx1 = N1PAD / 256;   // 24
  const int SPMM_GRID = 2048;

  // Segments (L1 gathers from padded-G tables; cols < N0/N1 only)
  Seg sg00_G = {rp00, sc00, sv00, G0, 1024, 0};
  Seg sg01_G = {rp01, sc01, sv01, G1, 1536, 0};
  Seg sg10_G = {rp10, sc10, sv10, G0, 1024, 512};
  Seg sg11a_G = {rp11a, sc11a, sv11a, G1, 1536, 512};
  Seg sg11b_G = {rp11b, sc11b, sv11b, G1, 1536, 1024};

  // --- Layer 1: GEMM-first, merged pair ---
  {
    GemmArgs ga = {feat0b, Wt1_0, G0, N0PAD, 1024, 1024, nbx0, 1024, nbx0 * 4};
    GemmArgs gb = {feat1b, Wt1_1, G1, N1PAD, 1536, 1024, nbx1, 1536, nbx1 * 6};
    gemm_pair<0><<<dim3(ga.nwg + gb.nwg), blk512, 0, stream>>>(ga, gb);
  }
  {
    Spmm1Set A = {N0, 2, sg00_G, sg01_G, Seg{}, e0_0, out};
    Spmm1Set B = {N1, 3, sg10_G, sg11a_G, sg11b_G, e0_1, out + (size_t)N0 * 1536};
    spmm1_pair<<<dim3(SPMM_GRID), blk, 0, stream>>>(A, B);
  }

  // --- Layer 2: SpMM-first, merged; K-concat GEMM + relu ---
  {
    Seg a0 = {rp00, sc00, sv00, e0_0, HDIM, 0};
    Seg a1 = {rp01, sc01, sv01, e0_1, HDIM, 0};
    Seg b0 = {rp10, sc10, sv10, e0_0, HDIM, 0};
    Seg b1 = {rp11a, sc11a, sv11a, e0_1, HDIM, 0};
    Seg b2 = {rp11b, sc11b, sv11b, e0_1, HDIM, 0};
    SepSet A = {N0, 2, a0, a1, Seg{}, G0, 1024};
    SepSet B = {N1, 3, b0, b1, b2, G1, 1536};
    spmm_sep_pair<<<dim3(SPMM_GRID), blk, 0, stream>>>(A, B);
  }
  {
    GemmArgs ga = {G0, Wt2_0, e2_0, N0PAD, 512, 1024, nbx0, 512, nbx0 * 2};
    GemmArgs gb = {G1, Wt2_1, e2_1, N1PAD, 512, 1536, nbx1, 512, nbx1 * 2};
    gemm_pair<1><<<dim3(ga.nwg + gb.nwg), blk512, 0, stream>>>(ga, gb);
  }

  // --- Layer 3: SpMM-first, merged; GEMM writes f32 NT into out cols [1024,1536) ---
  {
    Seg a0 = {rp00, sc00, sv00, e2_0, HDIM, 0};
    Seg a1 = {rp01, sc01, sv01, e2_1, HDIM, 0};
    Seg b0 = {rp10, sc10, sv10, e2_0, HDIM, 0};
    Seg b1 = {rp11a, sc11a, sv11a, e2_1, HDIM, 0};
    Seg b2 = {rp11b, sc11b, sv11b, e2_1, HDIM, 0};
    SepSet A = {N0, 2, a0, a1, Seg{}, G0, 1024};
    SepSet B = {N1, 3, b0, b1, b2, G1, 1536};
    spmm_sep_pair<<<dim3(SPMM_GRID), blk, 0, stream>>>(A, B);
  }
  {
    GemmArgs ga = {G0, Wt3_0, out + 1024, N0, 512, 1024, nbx0, 1536, nbx0 * 2};
    GemmArgs gb = {G1, Wt3_1, out + (size_t)N0 * 1536 + 1024, N1, 512, 1536, nbx1, 1536, nbx1 * 2};
    gemm_pair<2><<<dim3(ga.nwg + gb.nwg), blk512, 0, stream>>>(ga, gb);
  }
}

// Round 9
// 1292.061 us; speedup vs baseline: 1.3256x; 1.0289x over previous
//
#include <hip/hip_runtime.h>
#include <stdint.h>

#define N0 30000
#define N1 6000
#define N0PAD 30208
#define N1PAD 6144
#define FDIM 1024
#define HDIM 512
#define E00 600000
#define E01 300000
#define E10 300000
#define E11A 400000
#define E11B 400000
#define NE_TOT (E00 + E01 + E10 + E11A + E11B)

typedef __attribute__((ext_vector_type(4))) float f32x4;
typedef __attribute__((ext_vector_type(8))) __bf16 bf16x8;

// ---------- helpers ----------
__device__ __forceinline__ unsigned short f2bf(float f) {
  unsigned u = __float_as_uint(f);
  u += 0x7fffu + ((u >> 16) & 1u);   // round-to-nearest-even
  return (unsigned short)(u >> 16);
}

__device__ __forceinline__ void gload16(const void* g, void* l) {
  __builtin_amdgcn_global_load_lds((const __attribute__((address_space(1))) void*)g,
                                   (__attribute__((address_space(3))) void*)l, 16, 0, 0);
}

// ---------- conversion kernels ----------
__global__ void conv_bf16_kernel(const float* __restrict__ src, unsigned short* __restrict__ dst, int n4) {
  int gid = blockIdx.x * blockDim.x + threadIdx.x;
  if (gid >= n4) return;
  float4 v = ((const float4*)src)[gid];
  ushort4 o;
  o.x = f2bf(v.x); o.y = f2bf(v.y); o.z = f2bf(v.z); o.w = f2bf(v.w);
  ((ushort4*)dst)[gid] = o;
}

// Layer-1 weights: N-stacked, Bt[n][k] (k = FDIM).
__global__ void conv_weights_kernel(const float* __restrict__ w00, const float* __restrict__ w10,
                                    const float* __restrict__ w01, const float* __restrict__ w11a,
                                    const float* __restrict__ w11b,
                                    unsigned short* __restrict__ dst0, unsigned short* __restrict__ dst1, int K) {
  int gid = blockIdx.x * blockDim.x + threadIdx.x;
  int total0 = 1024 * K;
  int total1 = 1536 * K;
  if (gid < total0) {
    int n = gid / K, k = gid - n * K;
    const float* w = (n < 512) ? w00 : w10;
    int nn = n & 511;
    dst0[gid] = f2bf(w[(size_t)k * 512 + nn]);
  } else if (gid < total0 + total1) {
    int g = gid - total0;
    int n = g / K, k = g - n * K;
    const float* w = (n < 512) ? w01 : ((n < 1024) ? w11a : w11b);
    int nn = n & 511;
    dst1[g] = f2bf(w[(size_t)k * 512 + nn]);
  }
}

// Layers-2/3 weights (both layers in ONE launch): K-stacked, Bt[n][k], n in [0,512).
__global__ void conv_wk2_kernel(const float* __restrict__ w200, const float* __restrict__ w201,
                                const float* __restrict__ w210, const float* __restrict__ w211a,
                                const float* __restrict__ w211b,
                                unsigned short* __restrict__ d20, unsigned short* __restrict__ d21,
                                const float* __restrict__ w300, const float* __restrict__ w301,
                                const float* __restrict__ w310, const float* __restrict__ w311a,
                                const float* __restrict__ w311b,
                                unsigned short* __restrict__ d30, unsigned short* __restrict__ d31) {
  int gid = blockIdx.x * blockDim.x + threadIdx.x;
  const int T0 = 512 * 1024;
  const int T1 = 512 * 1536;
  const int TL = T0 + T1;
  const float* w00; const float* w01; const float* w10; const float* w11a; const float* w11b;
  unsigned short* dst0; unsigned short* dst1;
  if (gid < TL) {
    w00 = w200; w01 = w201; w10 = w210; w11a = w211a; w11b = w211b; dst0 = d20; dst1 = d21;
  } else if (gid < 2 * TL) {
    gid -= TL;
    w00 = w300; w01 = w301; w10 = w310; w11a = w311a; w11b = w311b; dst0 = d30; dst1 = d31;
  } else return;
  if (gid < T0) {
    int n = gid >> 10, k = gid & 1023;
    const float* w = (k < 512) ? w00 : w01;
    dst0[gid] = f2bf(w[(size_t)(k & 511) * 512 + n]);
  } else {
    int g = gid - T0;
    int n = g / 1536, k = g - n * 1536;
    const float* w = (k < 512) ? w10 : ((k < 1024) ? w11a : w11b);
    dst1[g] = f2bf(w[(size_t)(k & 511) * 512 + n]);
  }
}

// ---------- CSR build ----------
__global__ void zero_ints(int* p, int n) {
  int g = blockIdx.x * blockDim.x + threadIdx.x;
  if (g < n) p[g] = 0;
}

__global__ void hist5(const int* __restrict__ r0, const int* __restrict__ r1, const int* __restrict__ r2,
                      const int* __restrict__ r3, const int* __restrict__ r4,
                      int* c0, int* c1, int* c2, int* c3, int* c4) {
  int g = blockIdx.x * blockDim.x + threadIdx.x;
  const int* r; int* c; int e;
  if (g < E00) { r = r0; c = c0; e = g; }
  else if (g < E00 + E01) { r = r1; c = c1; e = g - E00; }
  else if (g < E00 + E01 + E10) { r = r2; c = c2; e = g - (E00 + E01); }
  else if (g < E00 + E01 + E10 + E11A) { r = r3; c = c3; e = g - (E00 + E01 + E10); }
  else if (g < NE_TOT) { r = r4; c = c4; e = g - (E00 + E01 + E10 + E11A); }
  else return;
  atomicAdd(&c[r[e]], 1);
}

__global__ __launch_bounds__(1024) void scan5p(int* c0, int* rp0, int* c1, int* rp1,
                                               int* c2, int* rp2, int* c3, int* rp3,
                                               int* c4, int* rp4) {
  int b = blockIdx.x;
  int* cnt; int* rp; int n;
  if (b == 0) { cnt = c0; rp = rp0; n = N0; }
  else if (b == 1) { cnt = c1; rp = rp1; n = N0; }
  else if (b == 2) { cnt = c2; rp = rp2; n = N1; }
  else if (b == 3) { cnt = c3; rp = rp3; n = N1; }
  else { cnt = c4; rp = rp4; n = N1; }
  __shared__ int wsum[16];
  const int tid = threadIdx.x, lane = tid & 63, w = tid >> 6;
  int carry = 0;
  for (int base = 0; base < n; base += 1024) {
    int i = base + tid;
    int v = (i < n) ? cnt[i] : 0;
    int x = v;
    #pragma unroll
    for (int d = 1; d < 64; d <<= 1) {
      int y = __shfl_up(x, d, 64);
      if (lane >= d) x += y;
    }
    if (lane == 63) wsum[w] = x;
    __syncthreads();
    if (w == 0) {
      int t = (lane < 16) ? wsum[lane] : 0;
      #pragma unroll
      for (int d = 1; d < 16; d <<= 1) {
        int y = __shfl_up(t, d, 64);
        if (lane >= d) t += y;
      }
      if (lane < 16) wsum[lane] = t;
    }
    __syncthreads();
    int wpref = (w > 0) ? wsum[w - 1] : 0;
    int excl = carry + wpref + (x - v);
    if (i < n) { rp[i] = excl; cnt[i] = excl; }
    carry += wsum[15];
    __syncthreads();
  }
  if (tid == 0) rp[n] = carry;
}

__global__ void scatter5(const int* __restrict__ r0, const int* __restrict__ q0, const float* __restrict__ v0,
                         int* cur0, int* sc0, float* sv0,
                         const int* __restrict__ r1, const int* __restrict__ q1, const float* __restrict__ v1,
                         int* cur1, int* sc1, float* sv1,
                         const int* __restrict__ r2, const int* __restrict__ q2, const float* __restrict__ v2,
                         int* cur2, int* sc2, float* sv2,
                         const int* __restrict__ r3, const int* __restrict__ q3, const float* __restrict__ v3,
                         int* cur3, int* sc3, float* sv3,
                         const int* __restrict__ r4, const int* __restrict__ q4, const float* __restrict__ v4,
                         int* cur4, int* sc4, float* sv4) {
  int g = blockIdx.x * blockDim.x + threadIdx.x;
  const int* r; const int* q; const float* v; int* cur; int* sc; float* sv; int e;
  if (g < E00) { r = r0; q = q0; v = v0; cur = cur0; sc = sc0; sv = sv0; e = g; }
  else if (g < E00 + E01) { r = r1; q = q1; v = v1; cur = cur1; sc = sc1; sv = sv1; e = g - E00; }
  else if (g < E00 + E01 + E10) { r = r2; q = q2; v = v2; cur = cur2; sc = sc2; sv = sv2; e = g - (E00 + E01); }
  else if (g < E00 + E01 + E10 + E11A) { r = r3; q = q3; v = v3; cur = cur3; sc = sc3; sv = sv3; e = g - (E00 + E01 + E10); }
  else if (g < NE_TOT) { r = r4; q = q4; v = v4; cur = cur4; sc = sc4; sv = sv4; e = g - (E00 + E01 + E10 + E11A); }
  else return;
  int row = r[e];
  int p = atomicAdd(&cur[row], 1);
  sc[p] = q[e];
  sv[p] = v[e];
}

// ---------- 256x256 pipelined bf16 MFMA GEMM: C = A[M][K] @ Bt[N][K]^T ----------
struct GemmArgs {
  const unsigned short* A;
  const unsigned short* Bt;
  void* C;
  int M, N, K, nbx, ldc, nwg;
};

template<int MODE>
__device__ __forceinline__ void gemm256_body(const GemmArgs& g, int orig) {
  __shared__ unsigned short lds[65536];  // 128 KB: buf b at b*32768 (A 16384 | B 16384)
  const int nwg = g.nwg;
  const int q = nwg >> 3, rr = nwg & 7;
  const int xcd = orig & 7, pos = orig >> 3;
  const int wg = (xcd < rr ? xcd * (q + 1) : rr * (q + 1) + (xcd - rr) * q) + pos;
  const int bx = wg % g.nbx;
  const int by = wg / g.nbx;

  const int tid = threadIdx.x;
  const int lane = tid & 63;
  const int wid = tid >> 6;
  const int wr = wid >> 2;
  const int wc = wid & 3;
  const int m0 = bx * 256;
  const int n0 = by * 256;
  const int K = g.K;
  const int nt = K >> 6;
  const int lo16 = lane & 15;
  const int hi = lane >> 4;

  f32x4 acc[8][4] = {};

  int srow[4], scol[4];
  #pragma unroll
  for (int i = 0; i < 4; i++) {
    int o = i * 4096 + tid * 8;
    int row = o >> 6;
    int c8 = (o >> 3) & 7;
    srow[i] = row;
    scol[i] = ((c8 ^ (row & 7)) * 8);
  }

  auto stage = [&](int kt, int b) {
    const unsigned short* Agl = g.A + (size_t)m0 * K + kt * 64;
    const unsigned short* Bgl = g.Bt + (size_t)n0 * K + kt * 64;
    unsigned short* Al = lds + b * 32768;
    unsigned short* Bl = Al + 16384;
    #pragma unroll
    for (int i = 0; i < 4; i++)
      gload16(Agl + (size_t)srow[i] * K + scol[i], Al + i * 4096 + tid * 8);
    #pragma unroll
    for (int i = 0; i < 4; i++)
      gload16(Bgl + (size_t)srow[i] * K + scol[i], Bl + i * 4096 + tid * 8);
  };

  stage(0, 0);
  stage(1, 1);
  asm volatile("s_waitcnt vmcnt(8)" ::: "memory");
  __builtin_amdgcn_s_barrier();
  __builtin_amdgcn_sched_barrier(0);

  for (int t = 0; t < nt; ++t) {
    const int cur = t & 1;
    const unsigned short* Ab = lds + cur * 32768;
    const unsigned short* Bb = Ab + 16384;

    bf16x8 bfr[4][2];
    #pragma unroll
    for (int n = 0; n < 4; n++)
      #pragma unroll
      for (int ks = 0; ks < 2; ks++) {
        int row = wc * 64 + n * 16 + lo16;
        int c8 = (ks * 4 + hi) ^ (row & 7);
        bfr[n][ks] = *(const bf16x8*)(Bb + row * 64 + c8 * 8);
      }
    #pragma unroll
    for (int h = 0; h < 2; h++) {
      bf16x8 af[4][2];
      #pragma unroll
      for (int m = 0; m < 4; m++)
        #pragma unroll
        for (int ks = 0; ks < 2; ks++) {
          int row = wr * 128 + (h * 4 + m) * 16 + lo16;
          int c8 = (ks * 4 + hi) ^ (row & 7);
          af[m][ks] = *(const bf16x8*)(Ab + row * 64 + c8 * 8);
        }
      if (h == 1) {
        asm volatile("s_waitcnt lgkmcnt(0)" ::: "memory");
        __builtin_amdgcn_sched_barrier(0);
        __builtin_amdgcn_s_barrier();
        __builtin_amdgcn_sched_barrier(0);
        if (t + 2 < nt) stage(t + 2, cur);
      }
      __builtin_amdgcn_s_setprio(1);
      #pragma unroll
      for (int m = 0; m < 4; m++)
        #pragma unroll
        for (int n = 0; n < 4; n++)
          #pragma unroll
          for (int ks = 0; ks < 2; ks++)
            acc[h * 4 + m][n] = __builtin_amdgcn_mfma_f32_16x16x32_bf16(
                af[m][ks], bfr[n][ks], acc[h * 4 + m][n], 0, 0, 0);
      __builtin_amdgcn_s_setprio(0);
    }
    if (t + 2 < nt) {
      asm volatile("s_waitcnt vmcnt(8)" ::: "memory");
    } else if (t + 1 < nt) {
      asm volatile("s_waitcnt vmcnt(0)" ::: "memory");
    }
    __builtin_amdgcn_s_barrier();
    __builtin_amdgcn_sched_barrier(0);
  }

  #pragma unroll
  for (int i = 0; i < 8; i++) {
    int rbase = m0 + wr * 128 + i * 16 + hi * 4;
    #pragma unroll
    for (int j = 0; j < 4; j++) {
      int col = n0 + wc * 64 + j * 16 + lo16;
      #pragma unroll
      for (int r = 0; r < 4; r++) {
        int row = rbase + r;
        if (row < g.M) {
          float v = acc[i][j][r];
          if (MODE == 1) v = fmaxf(v, 0.f);
          if (MODE == 2)
            __builtin_nontemporal_store(v, &((float*)g.C)[(size_t)row * g.ldc + col]);
          else
            ((unsigned short*)g.C)[(size_t)row * g.ldc + col] = f2bf(v);
        }
      }
    }
  }
}

template<int MODE>
__global__ __launch_bounds__(512, 2) void gemm_pair(GemmArgs ga, GemmArgs gb) {
  if ((int)blockIdx.x < ga.nwg) gemm256_body<MODE>(ga, blockIdx.x);
  else gemm256_body<MODE>(gb, blockIdx.x - ga.nwg);
}

// ---------- SpMM gather core ----------
__device__ __forceinline__ void acc8(float* acc, float v, const uint4& u) {
  acc[0] += v * __uint_as_float(u.x << 16);
  acc[1] += v * __uint_as_float(u.x & 0xffff0000u);
  acc[2] += v * __uint_as_float(u.y << 16);
  acc[3] += v * __uint_as_float(u.y & 0xffff0000u);
  acc[4] += v * __uint_as_float(u.z << 16);
  acc[5] += v * __uint_as_float(u.z & 0xffff0000u);
  acc[6] += v * __uint_as_float(u.w << 16);
  acc[7] += v * __uint_as_float(u.w & 0xffff0000u);
}

__device__ __forceinline__ void gather_row(const int* __restrict__ ci, const float* __restrict__ cv,
                                           const unsigned short* __restrict__ gb, int ld,
                                           int e, int e1, float* acc) {
  for (; e + 7 < e1; e += 8) {
    int c0 = ci[e], c1 = ci[e + 1], c2 = ci[e + 2], c3 = ci[e + 3];
    int c4 = ci[e + 4], c5 = ci[e + 5], c6 = ci[e + 6], c7 = ci[e + 7];
    float v0 = cv[e], v1 = cv[e + 1], v2 = cv[e + 2], v3 = cv[e + 3];
    float v4 = cv[e + 4], v5 = cv[e + 5], v6 = cv[e + 6], v7 = cv[e + 7];
    uint4 u0 = *(const uint4*)(gb + (size_t)c0 * ld);
    uint4 u1 = *(const uint4*)(gb + (size_t)c1 * ld);
    uint4 u2 = *(const uint4*)(gb + (size_t)c2 * ld);
    uint4 u3 = *(const uint4*)(gb + (size_t)c3 * ld);
    uint4 u4 = *(const uint4*)(gb + (size_t)c4 * ld);
    uint4 u5 = *(const uint4*)(gb + (size_t)c5 * ld);
    uint4 u6 = *(const uint4*)(gb + (size_t)c6 * ld);
    uint4 u7 = *(const uint4*)(gb + (size_t)c7 * ld);
    acc8(acc, v0, u0); acc8(acc, v1, u1); acc8(acc, v2, u2); acc8(acc, v3, u3);
    acc8(acc, v4, u4); acc8(acc, v5, u5); acc8(acc, v6, u6); acc8(acc, v7, u7);
  }
  for (; e < e1; ++e) {
    int c = ci[e];
    float v = cv[e];
    uint4 u = *(const uint4*)(gb + (size_t)c * ld);
    acc8(acc, v, u);
  }
}

struct Seg {
  const int* rp; const int* ci; const float* cv;
  const unsigned short* tbl; int ld; int off;
};

__device__ __forceinline__ void gather_seg(const Seg& s, int r, int lane, float* acc) {
  int e = __builtin_amdgcn_readfirstlane(s.rp[r]);
  int e1 = __builtin_amdgcn_readfirstlane(s.rp[r + 1]);
  gather_row(s.ci, s.cv, s.tbl + s.off + lane * 8, s.ld, e, e1, acc);
}

struct Spmm1Set {
  int nrows, nseg;
  Seg s0, s1, s2;
  unsigned short* ebf;   // bf16 e0 (ld 512)
  float* outp;           // f32 out base (row 0 of this set), ld 1536, dup at +512
};

// Layer-1 merged SpMM. HEAVY B (N1, ~183 edges/row) rows are scheduled FIRST:
// r0 < B.nrows -> B row; else A row (fixes the 37%-occupancy retirement tail).
__global__ __launch_bounds__(256) void spmm1_pair(Spmm1Set A, Spmm1Set B) {
  const int lane = threadIdx.x & 63;
  const int gw = blockIdx.x * 4 + (threadIdx.x >> 6);
  const int W = gridDim.x * 4;
  const int total = A.nrows + B.nrows;
  for (int r0 = gw; r0 < total; r0 += W) {
    bool useA = (r0 >= B.nrows);
    int r = useA ? r0 - B.nrows : r0;
    float acc[8] = {0.f, 0.f, 0.f, 0.f, 0.f, 0.f, 0.f, 0.f};
    {
      Seg s = useA ? A.s0 : B.s0;
      gather_seg(s, r, lane, acc);
    }
    {
      Seg s = useA ? A.s1 : B.s1;
      gather_seg(s, r, lane, acc);
    }
    if (!useA) {
      gather_seg(B.s2, r, lane, acc);
    }
    #pragma unroll
    for (int i = 0; i < 8; i++) acc[i] = fmaxf(acc[i], 0.f);
    unsigned short* ebf = useA ? A.ebf : B.ebf;
    float* outp = useA ? A.outp : B.outp;
    uint4 o;
    o.x = (unsigned)f2bf(acc[0]) | ((unsigned)f2bf(acc[1]) << 16);
    o.y = (unsigned)f2bf(acc[2]) | ((unsigned)f2bf(acc[3]) << 16);
    o.z = (unsigned)f2bf(acc[4]) | ((unsigned)f2bf(acc[5]) << 16);
    o.w = (unsigned)f2bf(acc[6]) | ((unsigned)f2bf(acc[7]) << 16);
    *(uint4*)(ebf + (size_t)r * HDIM + lane * 8) = o;
    f32x4 v0 = {acc[0], acc[1], acc[2], acc[3]};
    f32x4 v1 = {acc[4], acc[5], acc[6], acc[7]};
    size_t base = (size_t)r * 1536 + lane * 8;
    __builtin_nontemporal_store(v0, (f32x4*)(outp + base));
    __builtin_nontemporal_store(v1, (f32x4*)(outp + base + 4));
    __builtin_nontemporal_store(v0, (f32x4*)(outp + base + 512));
    __builtin_nontemporal_store(v1, (f32x4*)(outp + base + 516));
  }
}

struct SepSet {
  int nrows, nseg;
  Seg s0, s1, s2;
  unsigned short* outp;
  int ldo;
};

// Layers-2/3 merged SpMM, heavy-B-first ordering.
__global__ __launch_bounds__(256) void spmm_sep_pair(SepSet A, SepSet B) {
  const int lane = threadIdx.x & 63;
  const int gw = blockIdx.x * 4 + (threadIdx.x >> 6);
  const int W = gridDim.x * 4;
  const int total = A.nrows + B.nrows;
  for (int r0 = gw; r0 < total; r0 += W) {
    bool useA = (r0 >= B.nrows);
    int r = useA ? r0 - B.nrows : r0;
    unsigned short* outp = useA ? A.outp : B.outp;
    int ldo = useA ? A.ldo : B.ldo;
    int nseg = useA ? A.nseg : B.nseg;
    #pragma unroll
    for (int sidx = 0; sidx < 3; ++sidx) {
      if (sidx >= nseg) break;
      Seg s = (sidx == 0) ? (useA ? A.s0 : B.s0)
            : (sidx == 1) ? (useA ? A.s1 : B.s1)
                          : (useA ? A.s2 : B.s2);
      float acc[8] = {0.f, 0.f, 0.f, 0.f, 0.f, 0.f, 0.f, 0.f};
      gather_seg(s, r, lane, acc);
      uint4 o;
      o.x = (unsigned)f2bf(acc[0]) | ((unsigned)f2bf(acc[1]) << 16);
      o.y = (unsigned)f2bf(acc[2]) | ((unsigned)f2bf(acc[3]) << 16);
      o.z = (unsigned)f2bf(acc[4]) | ((unsigned)f2bf(acc[5]) << 16);
      o.w = (unsigned)f2bf(acc[6]) | ((unsigned)f2bf(acc[7]) << 16);
      *(uint4*)(outp + (size_t)r * ldo + sidx * HDIM + lane * 8) = o;
    }
  }
}

// ---------- host ----------
extern "C" void kernel_launch(void* const* d_in, const int* in_sizes, int n_in,
                              void* d_out, int out_size, void* d_ws, size_t ws_size,
                              hipStream_t stream) {
  const float* feat0 = (const float*)d_in[0];
  const float* feat1 = (const float*)d_in[1];
  const int* a00_row = (const int*)d_in[2];
  const int* a00_col = (const int*)d_in[3];
  const float* a00_val = (const float*)d_in[4];
  const int* a01_row = (const int*)d_in[5];
  const int* a01_col = (const int*)d_in[6];
  const float* a01_val = (const float*)d_in[7];
  const int* a10_row = (const int*)d_in[8];
  const int* a10_col = (const int*)d_in[9];
  const float* a10_val = (const float*)d_in[10];
  const int* a11a_row = (const int*)d_in[11];
  const int* a11a_col = (const int*)d_in[12];
  const float* a11a_val = (const float*)d_in[13];
  const int* a11b_row = (const int*)d_in[14];
  const int* a11b_col = (const int*)d_in[15];
  const float* a11b_val = (const float*)d_in[16];

  const float *W1[5], *W2[5], *W3[5];  // order: 00, 01, 10, 11a, 11b
  if (in_sizes[18] == 512 * 512) {
    for (int r = 0; r < 5; r++) {
      W1[r] = (const float*)d_in[17 + 3 * r];
      W2[r] = (const float*)d_in[18 + 3 * r];
      W3[r] = (const float*)d_in[19 + 3 * r];
    }
  } else {
    for (int r = 0; r < 5; r++) {
      W1[r] = (const float*)d_in[17 + r];
      W2[r] = (const float*)d_in[22 + r];
      W3[r] = (const float*)d_in[27 + r];
    }
  }

  char* ws = (char*)d_ws;
  size_t off = 0;
  auto alloc = [&](size_t bytes) -> char* {
    char* p = ws + off;
    off += (bytes + 255) & ~(size_t)255;
    return p;
  };
  unsigned short* feat0b = (unsigned short*)alloc((size_t)N0PAD * FDIM * 2);  // reused as e2_0
  unsigned short* feat1b = (unsigned short*)alloc((size_t)N1PAD * FDIM * 2);  // reused as e2_1
  unsigned short* Wt1_0 = (unsigned short*)alloc((size_t)1024 * 1024 * 2);
  unsigned short* Wt1_1 = (unsigned short*)alloc((size_t)1536 * 1024 * 2);
  unsigned short* Wt2_0 = (unsigned short*)alloc((size_t)512 * 1024 * 2);
  unsigned short* Wt2_1 = (unsigned short*)alloc((size_t)512 * 1536 * 2);
  unsigned short* Wt3_0 = (unsigned short*)alloc((size_t)512 * 1024 * 2);
  unsigned short* Wt3_1 = (unsigned short*)alloc((size_t)512 * 1536 * 2);
  unsigned short* G0 = (unsigned short*)alloc((size_t)N0PAD * 1024 * 2);
  unsigned short* G1 = (unsigned short*)alloc((size_t)N1PAD * 1536 * 2);
  unsigned short* e0_0 = (unsigned short*)alloc((size_t)N0 * HDIM * 2);
  unsigned short* e0_1 = (unsigned short*)alloc((size_t)N1 * HDIM * 2);
  int* cur = (int*)alloc((size_t)(2 * N0 + 3 * N1) * 4);
  int* cur00 = cur;
  int* cur01 = cur + N0;
  int* cur10 = cur + 2 * N0;
  int* cur11a = cur + 2 * N0 + N1;
  int* cur11b = cur + 2 * N0 + 2 * N1;
  int* rp00 = (int*)alloc((N0 + 1) * 4);
  int* rp01 = (int*)alloc((N0 + 1) * 4);
  int* rp10 = (int*)alloc((N1 + 1) * 4);
  int* rp11a = (int*)alloc((N1 + 1) * 4);
  int* rp11b = (int*)alloc((N1 + 1) * 4);
  int* sc00 = (int*)alloc((size_t)E00 * 4);
  float* sv00 = (float*)alloc((size_t)E00 * 4);
  int* sc01 = (int*)alloc((size_t)E01 * 4);
  float* sv01 = (float*)alloc((size_t)E01 * 4);
  int* sc10 = (int*)alloc((size_t)E10 * 4);
  float* sv10 = (float*)alloc((size_t)E10 * 4);
  int* sc11a = (int*)alloc((size_t)E11A * 4);
  float* sv11a = (float*)alloc((size_t)E11A * 4);
  int* sc11b = (int*)alloc((size_t)E11B * 4);
  float* sv11b = (float*)alloc((size_t)E11B * 4);
  unsigned short* e2_0 = feat0b;
  unsigned short* e2_1 = feat1b;
  float* out = (float*)d_out;

  // --- conversions ---
  conv_bf16_kernel<<<(N0 * FDIM / 4 + 255) / 256, 256, 0, stream>>>(feat0, feat0b, N0 * FDIM / 4);
  conv_bf16_kernel<<<(N1 * FDIM / 4 + 255) / 256, 256, 0, stream>>>(feat1, feat1b, N1 * FDIM / 4);
  conv_weights_kernel<<<(2560 * 1024 + 255) / 256, 256, 0, stream>>>(W1[0], W1[2], W1[1], W1[3], W1[4], Wt1_0, Wt1_1, 1024);
  conv_wk2_kernel<<<(2 * 512 * 2560 + 255) / 256, 256, 0, stream>>>(
      W2[0], W2[1], W2[2], W2[3], W2[4], Wt2_0, Wt2_1,
      W3[0], W3[1], W3[2], W3[3], W3[4], Wt3_0, Wt3_1);

  // --- CSR build ---
  int ncur = 2 * N0 + 3 * N1;
  zero_ints<<<(ncur + 255) / 256, 256, 0, stream>>>(cur, ncur);
  hist5<<<(NE_TOT + 255) / 256, 256, 0, stream>>>(a00_row, a01_row, a10_row, a11a_row, a11b_row,
                                                  cur00, cur01, cur10, cur11a, cur11b);
  scan5p<<<5, 1024, 0, stream>>>(cur00, rp00, cur01, rp01, cur10, rp10, cur11a, rp11a, cur11b, rp11b);
  scatter5<<<(NE_TOT + 255) / 256, 256, 0, stream>>>(
      a00_row, a00_col, a00_val, cur00, sc00, sv00,
      a01_row, a01_col, a01_val, cur01, sc01, sv01,
      a10_row, a10_col, a10_val, cur10, sc10, sv10,
      a11a_row, a11a_col, a11a_val, cur11a, sc11a, sv11a,
      a11b_row, a11b_col, a11b_val, cur11b, sc11b, sv11b);

  dim3 blk512(512);
  dim3 blk(256);
  int nbx0 = N0PAD / 256;   // 118
  int nbx1 = N1PAD / 256;   // 24
  const int SPMM_GRID = 2048;

  Seg sg00_G = {rp00, sc00, sv00, G0, 1024, 0};
  Seg sg01_G = {rp01, sc01, sv01, G1, 1536, 0};
  Seg sg10_G = {rp10, sc10, sv10, G0, 1024, 512};
  Seg sg11a_G = {rp11a, sc11a, sv11a, G1, 1536, 512};
  Seg sg11b_G = {rp11b, sc11b, sv11b, G1, 1536, 1024};

  // --- Layer 1: GEMM-first, merged pair ---
  {
    GemmArgs ga = {feat0b, Wt1_0, G0, N0PAD, 1024, 1024, nbx0, 1024, nbx0 * 4};
    GemmArgs gb = {feat1b, Wt1_1, G1, N1PAD, 1536, 1024, nbx1, 1536, nbx1 * 6};
    gemm_pair<0><<<dim3(ga.nwg + gb.nwg), blk512, 0, stream>>>(ga, gb);
  }
  {
    Spmm1Set A = {N0, 2, sg00_G, sg01_G, Seg{}, e0_0, out};
    Spmm1Set B = {N1, 3, sg10_G, sg11a_G, sg11b_G, e0_1, out + (size_t)N0 * 1536};
    spmm1_pair<<<dim3(SPMM_GRID), blk, 0, stream>>>(A, B);
  }

  // --- Layer 2: SpMM-first, merged; K-concat GEMM + relu ---
  {
    Seg a0 = {rp00, sc00, sv00, e0_0, HDIM, 0};
    Seg a1 = {rp01, sc01, sv01, e0_1, HDIM, 0};
    Seg b0 = {rp10, sc10, sv10, e0_0, HDIM, 0};
    Seg b1 = {rp11a, sc11a, sv11a, e0_1, HDIM, 0};
    Seg b2 = {rp11b, sc11b, sv11b, e0_1, HDIM, 0};
    SepSet A = {N0, 2, a0, a1, Seg{}, G0, 1024};
    SepSet B = {N1, 3, b0, b1, b2, G1, 1536};
    spmm_sep_pair<<<dim3(SPMM_GRID), blk, 0, stream>>>(A, B);
  }
  {
    GemmArgs ga = {G0, Wt2_0, e2_0, N0PAD, 512, 1024, nbx0, 512, nbx0 * 2};
    GemmArgs gb = {G1, Wt2_1, e2_1, N1PAD, 512, 1536, nbx1, 512, nbx1 * 2};
    gemm_pair<1><<<dim3(ga.nwg + gb.nwg), blk512, 0, stream>>>(ga, gb);
  }

  // --- Layer 3: SpMM-first, merged; GEMM writes f32 NT into out cols [1024,1536) ---
  {
    Seg a0 = {rp00, sc00, sv00, e2_0, HDIM, 0};
    Seg a1 = {rp01, sc01, sv01, e2_1, HDIM, 0};
    Seg b0 = {rp10, sc10, sv10, e2_0, HDIM, 0};
    Seg b1 = {rp11a, sc11a, sv11a, e2_1, HDIM, 0};
    Seg b2 = {rp11b, sc11b, sv11b, e2_1, HDIM, 0};
    SepSet A = {N0, 2, a0, a1, Seg{}, G0, 1024};
    SepSet B = {N1, 3, b0, b1, b2, G1, 1536};
    spmm_sep_pair<<<dim3(SPMM_GRID), blk, 0, stream>>>(A, B);
  }
  {
    GemmArgs ga = {G0, Wt3_0, out + 1024, N0, 512, 1024, nbx0, 1536, nbx0 * 2};
    GemmArgs gb = {G1, Wt3_1, out + (size_t)N0 * 1536 + 1024, N1, 512, 1536, nbx1, 1536, nbx1 * 2};
    gemm_pair<2><<<dim3(ga.nwg + gb.nwg), blk512, 0, stream>>>(ga, gb);
  }
}